// Round 13
// baseline (480.256 us; speedup 1.0000x reference)
//
#include <hip/hip_runtime.h>
#include <hip/hip_bf16.h>

#define B_ 4
#define N_ 1024
#define D_ 1024
#define H_ 16
#define DH_ 64
#define E_ 2112
#define ROWS_ 4096

typedef __bf16 bf16_t;
typedef bf16_t bf16x4 __attribute__((ext_vector_type(4)));
typedef bf16_t bf16x8 __attribute__((ext_vector_type(8)));
typedef float f32x4 __attribute__((ext_vector_type(4)));

__device__ __forceinline__ void gload_lds16(const void* g, void* l) {
  __builtin_amdgcn_global_load_lds(
      (const __attribute__((address_space(1))) void*)g,
      (__attribute__((address_space(3))) void*)l, 16, 0, 0);
}

// ---------------------------------------------------------------------------
// prep_all: flat grid merging 5 independent prep stages.
//  [0,1024):    conv_x   x fp32 -> xb bf16
//  [1024,2048): conv_wp  Wp[k][n] -> Wpt[n][k] bf16
//  [2048,3072): conv_wv  W[h][d][2048+dh] -> Wvt[h][dh][d] bf16
//  [3072,3088): bqk[h] = bq . bk
//  [3088,4112): conv_wqk (Wkb/Wqb bf16 + bias-dot vectors wqbk/wkbq)
// ---------------------------------------------------------------------------
__global__ __launch_bounds__(256)
void prep_all(const float* __restrict__ x, const float* __restrict__ Wp,
              const float* __restrict__ W, const float* __restrict__ bkqv,
              bf16_t* __restrict__ xb, bf16_t* __restrict__ Wpt,
              bf16_t* __restrict__ Wvt, float* __restrict__ bqk,
              bf16_t* __restrict__ Wqb, bf16_t* __restrict__ Wkb,
              float* __restrict__ wqbk, float* __restrict__ wkbq) {
  __shared__ float smem[2592];
  const int bid = blockIdx.x;
  const int t = threadIdx.x;
  if (bid < 1024) {
    const int n4 = ROWS_ * D_ / 4;
    for (int i = bid * 256 + t; i < n4; i += 1024 * 256) {
      float4 v = ((const float4*)x)[i];
      bf16x4 o = {(bf16_t)v.x, (bf16_t)v.y, (bf16_t)v.z, (bf16_t)v.w};
      ((bf16x4*)xb)[i] = o;
    }
  } else if (bid < 2048) {
    const int id = bid - 1024;
    const int nt = id & 31, kt = id >> 5;
    const int tx = t & 31, ty = t >> 5;
    #pragma unroll
    for (int rr = 0; rr < 4; ++rr)
      smem[(rr * 8 + ty) * 33 + tx] =
          Wp[(size_t)(kt * 32 + rr * 8 + ty) * D_ + nt * 32 + tx];
    __syncthreads();
    #pragma unroll
    for (int rr = 0; rr < 4; ++rr)
      Wpt[(size_t)(nt * 32 + rr * 8 + ty) * D_ + kt * 32 + tx] =
          (bf16_t)smem[tx * 33 + rr * 8 + ty];
  } else if (bid < 3072) {
    const int id = bid - 2048;
    const int et = id & 1, dt = (id >> 1) & 31, h = id >> 6;
    const int tx = t & 31, ty = t >> 5;
    const float* Wh = W + (size_t)h * D_ * E_;
    #pragma unroll
    for (int rr = 0; rr < 4; ++rr) {
      int d = dt * 32 + rr * 8 + ty;
      int dh = et * 32 + tx;
      smem[(rr * 8 + ty) * 33 + tx] = Wh[(size_t)d * E_ + 2048 + dh];
    }
    __syncthreads();
    bf16_t* Wvo = Wvt + (size_t)h * DH_ * D_;
    #pragma unroll
    for (int rr = 0; rr < 4; ++rr) {
      int dh = et * 32 + rr * 8 + ty;
      int d = dt * 32 + tx;
      Wvo[(size_t)dh * D_ + d] = (bf16_t)smem[tx * 33 + rr * 8 + ty];
    }
  } else if (bid < 3088) {
    const int h = bid - 3072;
    const float* bk = bkqv + h * E_;
    const float* bq = bk + 1024;
    float4 a = *(const float4*)(bk + t * 4);
    float4 b = *(const float4*)(bq + t * 4);
    smem[t] = a.x * b.x + a.y * b.y + a.z * b.z + a.w * b.w;
    __syncthreads();
    for (int st = 128; st > 0; st >>= 1) {
      if (t < st) smem[t] += smem[t + st];
      __syncthreads();
    }
    if (t == 0) bqk[h] = smem[0];
  } else {
    const int id = bid - 3088;
    const int db = id & 63, h = id >> 6;
    const float* Wh = W + (size_t)h * D_ * E_;
    float* bkL = smem;            // [1024]
    float* bqL = smem + 1024;     // [1024]
    float* red = smem + 2048;     // [2][16*17]
    for (int i = t; i < 1024; i += 256) {
      bkL[i] = bkqv[h * E_ + i];
      bqL[i] = bkqv[h * E_ + 1024 + i];
    }
    __syncthreads();
    const int rt = t >> 4, ct = t & 15;
    const int d = db * 16 + rt;
    const float* rowp = Wh + (size_t)d * E_;
    float pk = 0.f, pq = 0.f;
    #pragma unroll
    for (int j = 0; j < 16; ++j) {
      int e4 = (ct + j * 16) * 4;
      float4 vk = *(const float4*)(rowp + e4);
      float4 vq = *(const float4*)(rowp + 1024 + e4);
      bf16x4 ok = {(bf16_t)vk.x, (bf16_t)vk.y, (bf16_t)vk.z, (bf16_t)vk.w};
      bf16x4 oq = {(bf16_t)vq.x, (bf16_t)vq.y, (bf16_t)vq.z, (bf16_t)vq.w};
      *(bf16x4*)(Wkb + ((size_t)h * 1024 + d) * 1024 + e4) = ok;
      *(bf16x4*)(Wqb + ((size_t)h * 1024 + d) * 1024 + e4) = oq;
      pk += vk.x * bqL[e4] + vk.y * bqL[e4 + 1] + vk.z * bqL[e4 + 2] + vk.w * bqL[e4 + 3];
      pq += vq.x * bkL[e4] + vq.y * bkL[e4 + 1] + vq.z * bkL[e4 + 2] + vq.w * bkL[e4 + 3];
    }
    red[0 * 272 + rt * 17 + ct] = pk;
    red[1 * 272 + rt * 17 + ct] = pq;
    __syncthreads();
    if (t < 32) {
      int which = t >> 4, r = t & 15;
      float s = 0.f;
      #pragma unroll
      for (int c2 = 0; c2 < 16; ++c2) s += red[which * 272 + r * 17 + c2];
      if (which == 0) wkbq[h * 1024 + db * 16 + r] = s;
      else            wqbk[h * 1024 + db * 16 + r] = s;
    }
  }
}

// ---------------------------------------------------------------------------
// uv_v: merged uv_kernel [0,1024) + v_gemm [1024,1536).
// ---------------------------------------------------------------------------
__global__ __launch_bounds__(256)
void uv_v(const float* __restrict__ x, const float* __restrict__ bqk,
          const float* __restrict__ wqbk, const float* __restrict__ wkbq,
          float* __restrict__ u, float* __restrict__ v,
          const bf16_t* __restrict__ xb, const bf16_t* __restrict__ Wvt,
          const float* __restrict__ bkqv, bf16_t* __restrict__ Vt) {
  __shared__ bf16_t As2[64 * 64];
  __shared__ bf16_t Bs2[128 * 64];
  const int bid = blockIdx.x;
  const int t = threadIdx.x;
  if (bid < 1024) {
    const int w = t >> 6, l = t & 63;
    const int rg = bid * 4 + w;
    const int b = rg >> 10, n = rg & 1023;
    const float* xr = x + (size_t)rg * 1024 + l * 16;
    float4 xv0 = *(const float4*)(xr);
    float4 xv1 = *(const float4*)(xr + 4);
    float4 xv2 = *(const float4*)(xr + 8);
    float4 xv3 = *(const float4*)(xr + 12);
    #pragma unroll
    for (int h = 0; h < 16; ++h) {
      const float* wq = wqbk + h * 1024 + l * 16;
      const float* wk = wkbq + h * 1024 + l * 16;
      float4 q0 = *(const float4*)(wq);
      float4 q1 = *(const float4*)(wq + 4);
      float4 q2 = *(const float4*)(wq + 8);
      float4 q3 = *(const float4*)(wq + 12);
      float4 k0 = *(const float4*)(wk);
      float4 k1 = *(const float4*)(wk + 4);
      float4 k2 = *(const float4*)(wk + 8);
      float4 k3 = *(const float4*)(wk + 12);
      float au = xv0.x * q0.x + xv0.y * q0.y + xv0.z * q0.z + xv0.w * q0.w
               + xv1.x * q1.x + xv1.y * q1.y + xv1.z * q1.z + xv1.w * q1.w
               + xv2.x * q2.x + xv2.y * q2.y + xv2.z * q2.z + xv2.w * q2.w
               + xv3.x * q3.x + xv3.y * q3.y + xv3.z * q3.z + xv3.w * q3.w;
      float av = xv0.x * k0.x + xv0.y * k0.y + xv0.z * k0.z + xv0.w * k0.w
               + xv1.x * k1.x + xv1.y * k1.y + xv1.z * k1.z + xv1.w * k1.w
               + xv2.x * k2.x + xv2.y * k2.y + xv2.z * k2.z + xv2.w * k2.w
               + xv3.x * k3.x + xv3.y * k3.y + xv3.z * k3.z + xv3.w * k3.w;
      #pragma unroll
      for (int s = 1; s < 64; s <<= 1) {
        au += __shfl_xor(au, s);
        av += __shfl_xor(av, s);
      }
      if (l == 0) {
        int bh = b * 16 + h;
        u[(size_t)bh * 1024 + n] = au + bqk[h];
        v[(size_t)bh * 1024 + n] = av;
      }
    }
    return;
  }
  // ---- v_gemm part
  const int id = bid - 1024;
  const int nt = id & 31, h = id >> 5;
  const int w = t >> 6, l = t & 63, l15 = l & 15, lg = l >> 4;
  const bf16_t* Wvh = Wvt + (size_t)h * DH_ * D_;
  const bf16_t* Bn = xb + (size_t)nt * 128 * D_;

  f32x4 acc[4][2] = {};
  const int rswz = (l15 & 7) << 4;

  for (int kb = 0; kb < 16; ++kb) {
    __syncthreads();
    #pragma unroll
    for (int i = 0; i < 2; ++i) {
      int idx = t + i * 256;
      int row = idx >> 3, c = idx & 7;
      gload_lds16(Wvh + (size_t)row * D_ + kb * 64 + ((c ^ (row & 7)) << 3),
                  (char*)As2 + idx * 16);
    }
    #pragma unroll
    for (int i = 0; i < 4; ++i) {
      int idx = t + i * 256;
      int row = idx >> 3, c = idx & 7;
      gload_lds16(Bn + (size_t)row * D_ + kb * 64 + ((c ^ (row & 7)) << 3),
                  (char*)Bs2 + idx * 16);
    }
    __syncthreads();
    #pragma unroll
    for (int ks = 0; ks < 2; ++ks) {
      const int cswz = (ks * 64 + lg * 16) ^ rswz;
      bf16x8 a[4], b[2];
      #pragma unroll
      for (int mi = 0; mi < 4; ++mi)
        a[mi] = *(const bf16x8*)((const char*)As2 + (mi * 16 + l15) * 128 + cswz);
      #pragma unroll
      for (int ni = 0; ni < 2; ++ni)
        b[ni] = *(const bf16x8*)((const char*)Bs2 + (w * 32 + ni * 16 + l15) * 128 + cswz);
      #pragma unroll
      for (int mi = 0; mi < 4; ++mi)
        #pragma unroll
        for (int ni = 0; ni < 2; ++ni)
          acc[mi][ni] = __builtin_amdgcn_mfma_f32_16x16x32_bf16(a[mi], b[ni], acc[mi][ni], 0, 0, 0);
    }
  }

  #pragma unroll
  for (int mi = 0; mi < 4; ++mi)
    #pragma unroll
    for (int r = 0; r < 4; ++r) {
      int dh = mi * 16 + lg * 4 + r;
      float bias = bkqv[h * E_ + 2048 + dh];
      #pragma unroll
      for (int ni = 0; ni < 2; ++ni) {
        int nn = nt * 128 + w * 32 + ni * 16 + l15;
        int b = nn >> 10, n = nn & (N_ - 1);
        int bh = b * H_ + h;
        Vt[((size_t)bh * DH_ + dh) * N_ + n] = (bf16_t)(acc[mi][ni][r] + bias);
      }
    }
}

// ---------------------------------------------------------------------------
// 256x256xK=1024 core, OVERLAPPED schedule: 2 barriers per K-tile.
// Per tile kt (reads from buf kt&1):
//   issue reads [b0(4), ae0(4), b1(4), ae1(4)]
//   lgkm(8)  -> MFMA c0 (ae0 x b0)      | covers ao0 latency
//   issue ao0(4)
//   lgkm(4)  -> MFMA c1 (ae1 x b1)
//   issue ao1(4)
//   lgkm(4)  -> MFMA c2 (ao0 x b0)
//   lgkm(0)  -> MFMA c3 (ao1 x b1)
//   barrier  [all waves' reads of buf kt&1 retired]
//   stage tile kt+2 -> buf kt&1 (8 gloads; safe: readers just drained)
//   vmcnt(8) [completes kt+1's staging, leaves kt+2's 8 in flight]
//   barrier
// Prologue: stage t0+t1 (16 loads), vmcnt(8) [t0 done], barrier.
// Tail: kt=14: no stage, vmcnt(0); kt=15: compute only.
// LDS reads now overlap MFMA within each wave (c0 runs while ao* inflight).
// ---------------------------------------------------------------------------
__device__ __forceinline__ void mm256_core(const bf16_t* __restrict__ Ag,
                                           const bf16_t* __restrict__ Bg,
                                           bf16_t* lds, f32x4 (&acc)[8][4]) {
  char* Asp = (char*)lds;
  char* Bsp = (char*)lds + 65536;
  const int t = threadIdx.x;
  const int w = t >> 6, l = t & 63, l15 = l & 15, lg = l >> 4;
  const int wm = w >> 2, wn = w & 3;

  const int lr = l >> 3;
  const int scol = ((l & 7) ^ lr) << 3;
  const bf16_t* bS = Bg + (size_t)(w * 8 + lr) * 1024 + scol;
  const int idxA = w * 8 + lr;
  const bf16_t* aS0 = Ag + (size_t)((idxA >> 4) * 32 + (idxA & 15)) * 1024 + scol;
  const bf16_t* aS1 = aS0 + (size_t)128 * 1024;

#define STG_ALL(bufi, ktv)                                                     \
  do {                                                                         \
    gload_lds16(bS + (size_t)0 * 1024 + (ktv) * 64,                            \
                Bsp + (bufi) * 32768 + w * 1024);                              \
    gload_lds16(bS + (size_t)64 * 1024 + (ktv) * 64,                           \
                Bsp + (bufi) * 32768 + 8192 + w * 1024);                       \
    gload_lds16(bS + (size_t)128 * 1024 + (ktv) * 64,                          \
                Bsp + (bufi) * 32768 + 16384 + w * 1024);                      \
    gload_lds16(bS + (size_t)192 * 1024 + (ktv) * 64,                          \
                Bsp + (bufi) * 32768 + 16384 + 8192 + w * 1024);               \
    gload_lds16(aS0 + (size_t)0 * 1024 + (ktv) * 64,                           \
                Asp + (bufi) * 32768 + w * 1024);                              \
    gload_lds16(aS1 + (size_t)0 * 1024 + (ktv) * 64,                           \
                Asp + (bufi) * 32768 + 8192 + w * 1024);                       \
    gload_lds16(aS0 + (size_t)16 * 1024 + (ktv) * 64,                          \
                Asp + (bufi) * 32768 + 16384 + w * 1024);                      \
    gload_lds16(aS1 + (size_t)16 * 1024 + (ktv) * 64,                          \
                Asp + (bufi) * 32768 + 16384 + 8192 + w * 1024);               \
  } while (0)

  STG_ALL(0, 0);
  STG_ALL(1, 1);
  asm volatile("s_waitcnt vmcnt(8)" ::: "memory");
  __builtin_amdgcn_s_barrier();

  const int rswz = (l15 & 7) << 4;
  const int bro = ((wn & 1) * 64 + l15) * 128;

#define TILE_STEP(KT, DO_STG, WVW, DO_ENDBAR)                                  \
  {                                                                            \
    const char* Ab = Asp + ((KT) & 1) * 32768;                                 \
    const char* Bb = Bsp + ((KT) & 1) * 32768 + (wn >> 1) * 16384;             \
    const int cs0 = (lg * 16) ^ rswz;                                          \
    const int cs1 = (64 + lg * 16) ^ rswz;                                     \
    bf16x8 b0[4], b1[4], ae0[4], ae1[4], ao0[4], ao1[4];                       \
    _Pragma("unroll") for (int ni = 0; ni < 4; ++ni)                           \
      b0[ni] = *(const bf16x8*)(Bb + bro + ni * 2048 + cs0);                   \
    _Pragma("unroll") for (int q = 0; q < 4; ++q)                              \
      ae0[q] = *(const bf16x8*)(Ab + ((wm * 4 + q) * 16 + l15) * 128 + cs0);   \
    _Pragma("unroll") for (int ni = 0; ni < 4; ++ni)                           \
      b1[ni] = *(const bf16x8*)(Bb + bro + ni * 2048 + cs1);                   \
    _Pragma("unroll") for (int q = 0; q < 4; ++q)                              \
      ae1[q] = *(const bf16x8*)(Ab + ((wm * 4 + q) * 16 + l15) * 128 + cs1);   \
    asm volatile("s_waitcnt lgkmcnt(8)" ::: "memory");                         \
    __builtin_amdgcn_s_setprio(1);                                             \
    _Pragma("unroll") for (int q = 0; q < 4; ++q)                              \
      _Pragma("unroll") for (int ni = 0; ni < 4; ++ni)                         \
        acc[2 * q][ni] = __builtin_amdgcn_mfma_f32_16x16x32_bf16(              \
            ae0[q], b0[ni], acc[2 * q][ni], 0, 0, 0);                          \
    __builtin_amdgcn_s_setprio(0);                                             \
    _Pragma("unroll") for (int q = 0; q < 4; ++q)                              \
      ao0[q] = *(const bf16x8*)(Ab + 16384 + ((wm * 4 + q) * 16 + l15) * 128 + cs0); \
    asm volatile("s_waitcnt lgkmcnt(4)" ::: "memory");                         \
    __builtin_amdgcn_s_setprio(1);                                             \
    _Pragma("unroll") for (int q = 0; q < 4; ++q)                              \
      _Pragma("unroll") for (int ni = 0; ni < 4; ++ni)                         \
        acc[2 * q][ni] = __builtin_amdgcn_mfma_f32_16x16x32_bf16(              \
            ae1[q], b1[ni], acc[2 * q][ni], 0, 0, 0);                          \
    __builtin_amdgcn_s_setprio(0);                                             \
    _Pragma("unroll") for (int q = 0; q < 4; ++q)                              \
      ao1[q] = *(const bf16x8*)(Ab + 16384 + ((wm * 4 + q) * 16 + l15) * 128 + cs1); \
    asm volatile("s_waitcnt lgkmcnt(4)" ::: "memory");                         \
    __builtin_amdgcn_s_setprio(1);                                             \
    _Pragma("unroll") for (int q = 0; q < 4; ++q)                              \
      _Pragma("unroll") for (int ni = 0; ni < 4; ++ni)                         \
        acc[2 * q + 1][ni] = __builtin_amdgcn_mfma_f32_16x16x32_bf16(          \
            ao0[q], b0[ni], acc[2 * q + 1][ni], 0, 0, 0);                      \
    __builtin_amdgcn_s_setprio(0);                                             \
    asm volatile("s_waitcnt lgkmcnt(0)" ::: "memory");                         \
    __builtin_amdgcn_s_setprio(1);                                             \
    _Pragma("unroll") for (int q = 0; q < 4; ++q)                              \
      _Pragma("unroll") for (int ni = 0; ni < 4; ++ni)                         \
        acc[2 * q + 1][ni] = __builtin_amdgcn_mfma_f32_16x16x32_bf16(          \
            ao1[q], b1[ni], acc[2 * q + 1][ni], 0, 0, 0);                      \
    __builtin_amdgcn_s_setprio(0);                                             \
    __builtin_amdgcn_s_barrier();                                              \
    if (DO_STG) STG_ALL((KT) & 1, (KT) + 2);                                   \
    WVW;                                                                       \
    if (DO_ENDBAR) __builtin_amdgcn_s_barrier();                               \
  }

#define WV8_ asm volatile("s_waitcnt vmcnt(8)" ::: "memory")
#define WV0_ asm volatile("s_waitcnt vmcnt(0)" ::: "memory")
#define WN_

  for (int kt = 0; kt < 14; ++kt) TILE_STEP(kt, 1, WV8_, 1);
  TILE_STEP(14, 0, WV0_, 1);
  TILE_STEP(15, 0, WN_, 0);

#undef TILE_STEP
#undef STG_ALL
#undef WV8_
#undef WV0_
#undef WN_
}

__device__ __forceinline__ int xchunk4(int colf) {
  int c = colf >> 2;
  return ((c ^ (c >> 3)) << 2) | (colf & 3);
}

__device__ __forceinline__ void epi256_bf16(f32x4 (&acc)[8][4], bf16_t* lds,
                                            bf16_t* dst, int rowstride) {
  const int t = threadIdx.x;
  const int l = t & 63, l15 = l & 15, lg = l >> 4;
  const int w = t >> 6;
  const int wm = w >> 2, wn = w & 3;
  float* Ct = (float*)lds;   // [64][258]
  const int cpair = t & 31;
  const int p0 = xchunk4(cpair * 8);
  const int p1 = xchunk4(cpair * 8 + 4);
  #pragma unroll
  for (int s = 0; s < 4; ++s) {
    __syncthreads();
    #pragma unroll
    for (int m2 = 0; m2 < 2; ++m2)
      #pragma unroll
      for (int ni = 0; ni < 4; ++ni)
        #pragma unroll
        for (int r = 0; r < 4; ++r)
          Ct[(wm * 32 + m2 * 16 + lg * 4 + r) * 258 +
             xchunk4(wn * 64 + ni * 16 + l15)] = acc[2 * s + m2][ni][r];
    __syncthreads();
    #pragma unroll
    for (int it = 0; it < 4; ++it) {
      int row64 = (t >> 5) + it * 16;
      int wmq = row64 >> 5, m2q = (row64 >> 4) & 1, r16 = row64 & 15;
      int c8 = cpair * 8;
      const float* r0 = &Ct[row64 * 258 + p0];
      const float* r1 = &Ct[row64 * 258 + p1];
      bf16x8 o = {(bf16_t)r0[0], (bf16_t)r0[1], (bf16_t)r0[2], (bf16_t)r0[3],
                  (bf16_t)r1[0], (bf16_t)r1[1], (bf16_t)r1[2], (bf16_t)r1[3]};
      int lrow = wmq * 128 + (2 * s + m2q) * 16 + r16;
      *(bf16x8*)(dst + (size_t)lrow * rowstride + c8) = o;
    }
  }
}

// ---------------------------------------------------------------------------
// m_gemm: MT[h][d'][d] = sum_e Wk[d'][e] Wq[d][e]
// ---------------------------------------------------------------------------
__global__ __launch_bounds__(512)
void m_gemm(const bf16_t* __restrict__ Wkb, const bf16_t* __restrict__ Wqb,
            bf16_t* __restrict__ MT) {
  __shared__ bf16_t lds[65536];
  const int bid = blockIdx.x;          // 256 blocks
  const int mb = bid & 3, nb = (bid >> 2) & 3, h = bid >> 4;
  f32x4 acc[8][4] = {};
  mm256_core(Wkb + ((size_t)h * 1024 + mb * 256) * 1024,
             Wqb + ((size_t)h * 1024 + nb * 256) * 1024, lds, acc);
  epi256_bf16(acc, lds,
              MT + ((size_t)h * 1024 + mb * 256) * 1024 + nb * 256, 1024);
}

// ---------------------------------------------------------------------------
// t_gemm: T[bh][i][d'] = sum_d x[b][i][d] MT[h][d'][d]
// ---------------------------------------------------------------------------
__global__ __launch_bounds__(512)
void t_gemm(const bf16_t* __restrict__ xb, const bf16_t* __restrict__ MT,
            bf16_t* __restrict__ T) {
  __shared__ bf16_t lds[65536];
  const int bid = blockIdx.x;                      // 1024 blocks
  const int lid = (bid & 7) * 128 + (bid >> 3);    // XCD swizzle
  const int mb = lid & 15, nb = (lid >> 4) & 3, h = lid >> 6;
  f32x4 acc[8][4] = {};
  mm256_core(xb + (size_t)mb * 256 * 1024,
             MT + ((size_t)h * 1024 + nb * 256) * 1024, lds, acc);
  const int b = mb >> 2;
  const int bh = b * 16 + h;
  epi256_bf16(acc, lds,
              T + (size_t)bh * 1024 * 1024 + (size_t)((mb & 3) * 256) * 1024 +
                  nb * 256, 1024);
}

// ---------------------------------------------------------------------------
// s_gemm256: S = (T.x^T + u_i + v_j) * SCALE, lower-triangle 256^2 tiles,
// all 64 bh (640 blocks); bf16 out.
// ---------------------------------------------------------------------------
__global__ __launch_bounds__(512)
void s_gemm256(const bf16_t* __restrict__ T, const bf16_t* __restrict__ xb,
               const float* __restrict__ u, const float* __restrict__ v,
               bf16_t* __restrict__ Sg) {
  __shared__ bf16_t lds[65536];
  const int bid = blockIdx.x;                 // 0..639
  const int lid = (bid & 7) * 80 + (bid >> 3);
  const int idx = lid % 10;
  const int bh = lid / 10;
  const int bb = bh >> 4;
  int qt = 0;
  while ((qt + 1) * (qt + 2) / 2 <= idx) ++qt;
  const int kt = idx - qt * (qt + 1) / 2;

  f32x4 acc[8][4] = {};
  mm256_core(T + (size_t)bh * 1024 * 1024 + (size_t)qt * 256 * 1024,
             xb + (size_t)bb * 1024 * 1024 + (size_t)kt * 256 * 1024, lds, acc);

  const int t = threadIdx.x;
  const int w = t >> 6, l = t & 63, l15 = l & 15, lg = l >> 4;
  const int wm = w >> 2, wn = w & 3;
  const float SCALE = 0.045084220027780106f;   // log2(e)/sqrt(1024)
  bf16_t* So = Sg + (((size_t)bh * 10 + idx) << 16);

  const float* ubh = u + (size_t)bh * 1024 + qt * 256;
  const float* vbh = v + (size_t)bh * 1024 + kt * 256;
  float vv[4];
  #pragma unroll
  for (int ni = 0; ni < 4; ++ni) vv[ni] = vbh[wn * 64 + ni * 16 + l15];

  #pragma unroll
  for (int mi = 0; mi < 8; ++mi)
    #pragma unroll
    for (int r = 0; r < 4; ++r) {
      int rl = wm * 128 + mi * 16 + lg * 4 + r;
      float uu = ubh[rl];
      #pragma unroll
      for (int ni = 0; ni < 4; ++ni) {
        int cl = wn * 64 + ni * 16 + l15;
        float z = (acc[mi][ni][r] + uu + vv[ni]) * SCALE;
        if (kt * 256 + cl > qt * 256 + rl) z = -1e30f;
        acc[mi][ni][r] = z;
      }
    }

  epi256_bf16(acc, lds, So, 256);
}

// ---------------------------------------------------------------------------
// softmax + P.V (bf16 S)
// ---------------------------------------------------------------------------
__global__ __launch_bounds__(256)
void softmax_pv(const bf16_t* __restrict__ Sg, const bf16_t* __restrict__ Vt,
                bf16_t* __restrict__ sa) {
  const int qt = blockIdx.x;   // 0..15
  const int bh = blockIdx.y;   // 0..63
  const int t = threadIdx.x;
  const int w = t >> 6, l = t & 63, l15 = l & 15, lg = l >> 4;
  const int b = bh >> 4, h = bh & 15;

  const int qrow = qt * 64 + w * 16 + l15;
  const int qt8 = qt >> 2;
  const bf16_t* Sbh = Sg + (((size_t)bh * 10) << 16);
  const bf16_t* Vh = Vt + (size_t)bh * DH_ * N_;

  f32x4 accO[4] = {};
  float m = -1e30f, lsum = 0.f;

  for (int j = 0; j <= qt; ++j) {
    const int jb = j * 64;
    const int tid = qt8 * (qt8 + 1) / 2 + (j >> 2);
    const bf16_t* Srow = Sbh + ((size_t)tid << 16) +
                         (size_t)(qrow & 255) * 256 + (jb & 255);

    bf16x8 h0 = *(const bf16x8*)(Srow + lg * 8);
    bf16x8 h1 = *(const bf16x8*)(Srow + 32 + lg * 8);
    float z[16];
    #pragma unroll
    for (int i = 0; i < 8; ++i) z[i] = (float)h0[i];
    #pragma unroll
    for (int i = 0; i < 8; ++i) z[8 + i] = (float)h1[i];

    float zm = z[0];
    #pragma unroll
    for (int i = 1; i < 16; ++i) zm = fmaxf(zm, z[i]);
    zm = fmaxf(zm, __shfl_xor(zm, 16));
    zm = fmaxf(zm, __shfl_xor(zm, 32));

    float mnew = fmaxf(m, zm);
    float scl = exp2f(m - mnew);
    m = mnew;

    float p[16];
    #pragma unroll
    for (int i = 0; i < 16; ++i) p[i] = exp2f(z[i] - mnew);

    float rs = 0.f;
    #pragma unroll
    for (int i = 0; i < 16; ++i) rs += p[i];
    rs += __shfl_xor(rs, 16);
    rs += __shfl_xor(rs, 32);
    lsum = lsum * scl + rs;

    float sclO[4];
    #pragma unroll
    for (int r = 0; r < 4; ++r) sclO[r] = __shfl(scl, lg * 4 + r);
    #pragma unroll
    for (int db = 0; db < 4; ++db)
      #pragma unroll
      for (int r = 0; r < 4; ++r) accO[db][r] *= sclO[r];

    bf16x8 pa0 = {(bf16_t)p[0], (bf16_t)p[1], (bf16_t)p[2], (bf16_t)p[3],
                  (bf16_t)p[4], (bf16_t)p[5], (bf16_t)p[6], (bf16_t)p[7]};
    bf16x8 pa1 = {(bf16_t)p[8], (bf16_t)p[9], (bf16_t)p[10], (bf16_t)p[11],
                  (bf16_t)p[12], (bf16_t)p[13], (bf16_t)p[14], (bf16_t)p[15]};

    #pragma unroll
    for (int db = 0; db < 4; ++db) {
      const bf16_t* vp = Vh + (size_t)(db * 16 + l15) * N_ + jb;
      bf16x8 vb0 = *(const bf16x8*)(vp + lg * 8);
      bf16x8 vb1 = *(const bf16x8*)(vp + 32 + lg * 8);
      accO[db] = __builtin_amdgcn_mfma_f32_16x16x32_bf16(pa0, vb0, accO[db], 0, 0, 0);
      accO[db] = __builtin_amdgcn_mfma_f32_16x16x32_bf16(pa1, vb1, accO[db], 0, 0, 0);
    }
  }

  float lO[4];
  #pragma unroll
  for (int r = 0; r < 4; ++r) lO[r] = __shfl(lsum, lg * 4 + r);

  #pragma unroll
  for (int db = 0; db < 4; ++db)
    #pragma unroll
    for (int r = 0; r < 4; ++r) {
      int row = qt * 64 + w * 16 + lg * 4 + r;
      int col = h * DH_ + db * 16 + l15;
      sa[((size_t)b * N_ + row) * D_ + col] = (bf16_t)(accO[db][r] / lO[r]);
    }
}

// ---------------------------------------------------------------------------
// out_gemm (m97 128^2 structure, fp32 out)
// ---------------------------------------------------------------------------
__global__ __launch_bounds__(256)
void out_gemm(const bf16_t* __restrict__ A, const bf16_t* __restrict__ Bt,
              const float* __restrict__ bp, float* __restrict__ out) {
  const int mb = blockIdx.x, nb = blockIdx.y;
  const int t = threadIdx.x;
  const int w = t >> 6, l = t & 63, l15 = l & 15, lg = l >> 4;
  const int wr = (w >> 1) * 64, wc = (w & 1) * 64;

  __shared__ bf16_t As[128 * 64];
  __shared__ bf16_t Bs[128 * 64];

  const int srow = w * 32 + (l >> 3);
  const int scol = (l & 7) * 8;
  const bf16_t* ag = A + (size_t)(mb * 128 + srow) * D_ + scol;
  const bf16_t* bg = Bt + (size_t)(nb * 128 + srow) * D_ + scol;
  char* asl = (char*)As + w * 4096;
  char* bsl = (char*)Bs + w * 4096;

  f32x4 acc[4][4] = {};

  for (int kb = 0; kb < 16; ++kb) {
    __syncthreads();
    #pragma unroll
    for (int i = 0; i < 4; ++i) {
      gload_lds16(ag + (size_t)i * 8 * D_ + kb * 64, asl + i * 1024);
      gload_lds16(bg + (size_t)i * 8 * D_ + kb * 64, bsl + i * 1024);
    }
    __syncthreads();
    #pragma unroll
    for (int ks = 0; ks < 2; ++ks) {
      bf16x8 a[4], b[4];
      #pragma unroll
      for (int mi = 0; mi < 4; ++mi)
        a[mi] = *(const bf16x8*)((const char*)As + (wr + mi * 16 + l15) * 128 + ks * 64 + lg * 16);
      #pragma unroll
      for (int ni = 0; ni < 4; ++ni)
        b[ni] = *(const bf16x8*)((const char*)Bs + (wc + ni * 16 + l15) * 128 + ks * 64 + lg * 16);
      #pragma unroll
      for (int mi = 0; mi < 4; ++mi)
        #pragma unroll
        for (int ni = 0; ni < 4; ++ni)
          acc[mi][ni] = __builtin_amdgcn_mfma_f32_16x16x32_bf16(a[mi], b[ni], acc[mi][ni], 0, 0, 0);
    }
  }

  #pragma unroll
  for (int ni = 0; ni < 4; ++ni) {
    int e = nb * 128 + wc + ni * 16 + l15;
    float bias = bp[e];
    #pragma unroll
    for (int mi = 0; mi < 4; ++mi)
      #pragma unroll
      for (int r = 0; r < 4; ++r) {
        int grow = mb * 128 + wr + mi * 16 + lg * 4 + r;
        out[(size_t)grow * D_ + e] = acc[mi][ni][r] + bias;
      }
  }
}

// ---------------------------------------------------------------------------
extern "C" void kernel_launch(void* const* d_in, const int* in_sizes, int n_in,
                              void* d_out, int out_size, void* d_ws, size_t ws_size,
                              hipStream_t stream) {
  const float* x    = (const float*)d_in[0];
  const float* Wkqv = (const float*)d_in[1];
  const float* bkqv = (const float*)d_in[2];
  const float* Wp   = (const float*)d_in[3];
  const float* bp   = (const float*)d_in[4];
  float* out = (float*)d_out;
  char* ws = (char*)d_ws;

  const size_t MB = 1 << 20;
  bf16_t* xb   = (bf16_t*)(ws);              //   8 MiB
  bf16_t* sa   = (bf16_t*)(ws + 8 * MB);     //   8 MiB
  bf16_t* Wpt  = (bf16_t*)(ws + 16 * MB);    //   2 MiB
  bf16_t* Vt   = (bf16_t*)(ws + 18 * MB);    //   8 MiB
  bf16_t* Wvt  = (bf16_t*)(ws + 26 * MB);    //   2 MiB
  bf16_t* MT   = (bf16_t*)(ws + 28 * MB);    //  32 MiB
  bf16_t* T    = (bf16_t*)(ws + 60 * MB);    // 128 MiB
  bf16_t* Wqb  = (bf16_t*)(ws + 188 * MB);   //  32 MiB (dead after m_gemm)
  bf16_t* Wkb  = (bf16_t*)(ws + 220 * MB);   //  32 MiB (dead after m_gemm)
  bf16_t* Sg   = (bf16_t*)(ws + 188 * MB);   //  80 MiB (reuses Wqb/Wkb)
  float*  u    = (float*) (ws + 268 * MB);               // 256 KiB
  float*  v    = (float*) (ws + 268 * MB + 256 * 1024);  // 256 KiB
  float*  wqbk = (float*) (ws + 268 * MB + 512 * 1024);  // 64 KiB
  float*  wkbq = (float*) (ws + 268 * MB + 576 * 1024);  // 64 KiB
  float*  bqk  = (float*) (ws + 268 * MB + 640 * 1024);  // 64 B
  // top < 269 MiB < proven-safe 285,212,672 B

  hipLaunchKernelGGL(prep_all, dim3(4112), dim3(256), 0, stream,
                     x, Wp, Wkqv, bkqv, xb, Wpt, Wvt, bqk,
                     Wqb, Wkb, wqbk, wkbq);
  hipLaunchKernelGGL(uv_v, dim3(1536), dim3(256), 0, stream,
                     x, bqk, wqbk, wkbq, u, v, xb, Wvt, bkqv, Vt);
  hipLaunchKernelGGL(m_gemm, dim3(256), dim3(512), 0, stream, Wkb, Wqb, MT);
  hipLaunchKernelGGL(t_gemm, dim3(1024), dim3(512), 0, stream, xb, MT, T);
  hipLaunchKernelGGL(s_gemm256, dim3(640), dim3(512), 0, stream,
                     T, xb, u, v, Sg);
  hipLaunchKernelGGL(softmax_pv, dim3(16, 64), dim3(256), 0, stream,
                     Sg, Vt, sa);
  hipLaunchKernelGGL(out_gemm, dim3(32, 8), dim3(256), 0, stream,
                     sa, Wpt, bp, out);
}

// Round 14
// 453.001 us; speedup vs baseline: 1.0602x; 1.0602x over previous
//
#include <hip/hip_runtime.h>
#include <hip/hip_bf16.h>

#define B_ 4
#define N_ 1024
#define D_ 1024
#define H_ 16
#define DH_ 64
#define E_ 2112
#define ROWS_ 4096

typedef __bf16 bf16_t;
typedef bf16_t bf16x4 __attribute__((ext_vector_type(4)));
typedef bf16_t bf16x8 __attribute__((ext_vector_type(8)));
typedef float f32x4 __attribute__((ext_vector_type(4)));

__device__ __forceinline__ void gload_lds16(const void* g, void* l) {
  __builtin_amdgcn_global_load_lds(
      (const __attribute__((address_space(1))) void*)g,
      (__attribute__((address_space(3))) void*)l, 16, 0, 0);
}

// ---------------------------------------------------------------------------
// prep_all: flat grid merging 5 independent prep stages.
//  [0,1024):    conv_x   x fp32 -> xb bf16
//  [1024,2048): conv_wp  Wp[k][n] -> Wpt[n][k] bf16
//  [2048,3072): conv_wv  W[h][d][2048+dh] -> Wvt[h][dh][d] bf16
//  [3072,3088): bqk[h] = bq . bk
//  [3088,4112): conv_wqk (Wkb/Wqb bf16 + bias-dot vectors wqbk/wkbq)
// ---------------------------------------------------------------------------
__global__ __launch_bounds__(256)
void prep_all(const float* __restrict__ x, const float* __restrict__ Wp,
              const float* __restrict__ W, const float* __restrict__ bkqv,
              bf16_t* __restrict__ xb, bf16_t* __restrict__ Wpt,
              bf16_t* __restrict__ Wvt, float* __restrict__ bqk,
              bf16_t* __restrict__ Wqb, bf16_t* __restrict__ Wkb,
              float* __restrict__ wqbk, float* __restrict__ wkbq) {
  __shared__ float smem[2592];
  const int bid = blockIdx.x;
  const int t = threadIdx.x;
  if (bid < 1024) {
    const int n4 = ROWS_ * D_ / 4;
    for (int i = bid * 256 + t; i < n4; i += 1024 * 256) {
      float4 v = ((const float4*)x)[i];
      bf16x4 o = {(bf16_t)v.x, (bf16_t)v.y, (bf16_t)v.z, (bf16_t)v.w};
      ((bf16x4*)xb)[i] = o;
    }
  } else if (bid < 2048) {
    const int id = bid - 1024;
    const int nt = id & 31, kt = id >> 5;
    const int tx = t & 31, ty = t >> 5;
    #pragma unroll
    for (int rr = 0; rr < 4; ++rr)
      smem[(rr * 8 + ty) * 33 + tx] =
          Wp[(size_t)(kt * 32 + rr * 8 + ty) * D_ + nt * 32 + tx];
    __syncthreads();
    #pragma unroll
    for (int rr = 0; rr < 4; ++rr)
      Wpt[(size_t)(nt * 32 + rr * 8 + ty) * D_ + kt * 32 + tx] =
          (bf16_t)smem[tx * 33 + rr * 8 + ty];
  } else if (bid < 3072) {
    const int id = bid - 2048;
    const int et = id & 1, dt = (id >> 1) & 31, h = id >> 6;
    const int tx = t & 31, ty = t >> 5;
    const float* Wh = W + (size_t)h * D_ * E_;
    #pragma unroll
    for (int rr = 0; rr < 4; ++rr) {
      int d = dt * 32 + rr * 8 + ty;
      int dh = et * 32 + tx;
      smem[(rr * 8 + ty) * 33 + tx] = Wh[(size_t)d * E_ + 2048 + dh];
    }
    __syncthreads();
    bf16_t* Wvo = Wvt + (size_t)h * DH_ * D_;
    #pragma unroll
    for (int rr = 0; rr < 4; ++rr) {
      int dh = et * 32 + rr * 8 + ty;
      int d = dt * 32 + tx;
      Wvo[(size_t)dh * D_ + d] = (bf16_t)smem[tx * 33 + rr * 8 + ty];
    }
  } else if (bid < 3088) {
    const int h = bid - 3072;
    const float* bk = bkqv + h * E_;
    const float* bq = bk + 1024;
    float4 a = *(const float4*)(bk + t * 4);
    float4 b = *(const float4*)(bq + t * 4);
    smem[t] = a.x * b.x + a.y * b.y + a.z * b.z + a.w * b.w;
    __syncthreads();
    for (int st = 128; st > 0; st >>= 1) {
      if (t < st) smem[t] += smem[t + st];
      __syncthreads();
    }
    if (t == 0) bqk[h] = smem[0];
  } else {
    const int id = bid - 3088;
    const int db = id & 63, h = id >> 6;
    const float* Wh = W + (size_t)h * D_ * E_;
    float* bkL = smem;            // [1024]
    float* bqL = smem + 1024;     // [1024]
    float* red = smem + 2048;     // [2][272]
    for (int i = t; i < 1024; i += 256) {
      bkL[i] = bkqv[h * E_ + i];
      bqL[i] = bkqv[h * E_ + 1024 + i];
    }
    __syncthreads();
    const int rt = t >> 4, ct = t & 15;
    const int d = db * 16 + rt;
    const float* rowp = Wh + (size_t)d * E_;
    float pk = 0.f, pq = 0.f;
    #pragma unroll
    for (int j = 0; j < 16; ++j) {
      int e4 = (ct + j * 16) * 4;
      float4 vk = *(const float4*)(rowp + e4);
      float4 vq = *(const float4*)(rowp + 1024 + e4);
      bf16x4 ok = {(bf16_t)vk.x, (bf16_t)vk.y, (bf16_t)vk.z, (bf16_t)vk.w};
      bf16x4 oq = {(bf16_t)vq.x, (bf16_t)vq.y, (bf16_t)vq.z, (bf16_t)vq.w};
      *(bf16x4*)(Wkb + ((size_t)h * 1024 + d) * 1024 + e4) = ok;
      *(bf16x4*)(Wqb + ((size_t)h * 1024 + d) * 1024 + e4) = oq;
      pk += vk.x * bqL[e4] + vk.y * bqL[e4 + 1] + vk.z * bqL[e4 + 2] + vk.w * bqL[e4 + 3];
      pq += vq.x * bkL[e4] + vq.y * bkL[e4 + 1] + vq.z * bkL[e4 + 2] + vq.w * bkL[e4 + 3];
    }
    red[0 * 272 + rt * 17 + ct] = pk;
    red[1 * 272 + rt * 17 + ct] = pq;
    __syncthreads();
    if (t < 32) {
      int which = t >> 4, r = t & 15;
      float s = 0.f;
      #pragma unroll
      for (int c2 = 0; c2 < 16; ++c2) s += red[which * 272 + r * 17 + c2];
      if (which == 0) wkbq[h * 1024 + db * 16 + r] = s;
      else            wqbk[h * 1024 + db * 16 + r] = s;
    }
  }
}

// ---------------------------------------------------------------------------
// uv_v: merged uv_kernel [0,1024) + v_gemm [1024,1536).
// ---------------------------------------------------------------------------
__global__ __launch_bounds__(256)
void uv_v(const float* __restrict__ x, const float* __restrict__ bqk,
          const float* __restrict__ wqbk, const float* __restrict__ wkbq,
          float* __restrict__ u, float* __restrict__ v,
          const bf16_t* __restrict__ xb, const bf16_t* __restrict__ Wvt,
          const float* __restrict__ bkqv, bf16_t* __restrict__ Vt) {
  __shared__ bf16_t As2[64 * 64];
  __shared__ bf16_t Bs2[128 * 64];
  const int bid = blockIdx.x;
  const int t = threadIdx.x;
  if (bid < 1024) {
    const int w = t >> 6, l = t & 63;
    const int rg = bid * 4 + w;
    const int b = rg >> 10, n = rg & 1023;
    const float* xr = x + (size_t)rg * 1024 + l * 16;
    float4 xv0 = *(const float4*)(xr);
    float4 xv1 = *(const float4*)(xr + 4);
    float4 xv2 = *(const float4*)(xr + 8);
    float4 xv3 = *(const float4*)(xr + 12);
    #pragma unroll
    for (int h = 0; h < 16; ++h) {
      const float* wq = wqbk + h * 1024 + l * 16;
      const float* wk = wkbq + h * 1024 + l * 16;
      float4 q0 = *(const float4*)(wq);
      float4 q1 = *(const float4*)(wq + 4);
      float4 q2 = *(const float4*)(wq + 8);
      float4 q3 = *(const float4*)(wq + 12);
      float4 k0 = *(const float4*)(wk);
      float4 k1 = *(const float4*)(wk + 4);
      float4 k2 = *(const float4*)(wk + 8);
      float4 k3 = *(const float4*)(wk + 12);
      float au = xv0.x * q0.x + xv0.y * q0.y + xv0.z * q0.z + xv0.w * q0.w
               + xv1.x * q1.x + xv1.y * q1.y + xv1.z * q1.z + xv1.w * q1.w
               + xv2.x * q2.x + xv2.y * q2.y + xv2.z * q2.z + xv2.w * q2.w
               + xv3.x * q3.x + xv3.y * q3.y + xv3.z * q3.z + xv3.w * q3.w;
      float av = xv0.x * k0.x + xv0.y * k0.y + xv0.z * k0.z + xv0.w * k0.w
               + xv1.x * k1.x + xv1.y * k1.y + xv1.z * k1.z + xv1.w * k1.w
               + xv2.x * k2.x + xv2.y * k2.y + xv2.z * k2.z + xv2.w * k2.w
               + xv3.x * k3.x + xv3.y * k3.y + xv3.z * k3.z + xv3.w * k3.w;
      #pragma unroll
      for (int s = 1; s < 64; s <<= 1) {
        au += __shfl_xor(au, s);
        av += __shfl_xor(av, s);
      }
      if (l == 0) {
        int bh = b * 16 + h;
        u[(size_t)bh * 1024 + n] = au + bqk[h];
        v[(size_t)bh * 1024 + n] = av;
      }
    }
    return;
  }
  // ---- v_gemm part
  const int id = bid - 1024;
  const int nt = id & 31, h = id >> 5;
  const int w = t >> 6, l = t & 63, l15 = l & 15, lg = l >> 4;
  const bf16_t* Wvh = Wvt + (size_t)h * DH_ * D_;
  const bf16_t* Bn = xb + (size_t)nt * 128 * D_;

  f32x4 acc[4][2] = {};
  const int rswz = (l15 & 7) << 4;

  for (int kb = 0; kb < 16; ++kb) {
    __syncthreads();
    #pragma unroll
    for (int i = 0; i < 2; ++i) {
      int idx = t + i * 256;
      int row = idx >> 3, c = idx & 7;
      gload_lds16(Wvh + (size_t)row * D_ + kb * 64 + ((c ^ (row & 7)) << 3),
                  (char*)As2 + idx * 16);
    }
    #pragma unroll
    for (int i = 0; i < 4; ++i) {
      int idx = t + i * 256;
      int row = idx >> 3, c = idx & 7;
      gload_lds16(Bn + (size_t)row * D_ + kb * 64 + ((c ^ (row & 7)) << 3),
                  (char*)Bs2 + idx * 16);
    }
    __syncthreads();
    #pragma unroll
    for (int ks = 0; ks < 2; ++ks) {
      const int cswz = (ks * 64 + lg * 16) ^ rswz;
      bf16x8 a[4], b[2];
      #pragma unroll
      for (int mi = 0; mi < 4; ++mi)
        a[mi] = *(const bf16x8*)((const char*)As2 + (mi * 16 + l15) * 128 + cswz);
      #pragma unroll
      for (int ni = 0; ni < 2; ++ni)
        b[ni] = *(const bf16x8*)((const char*)Bs2 + (w * 32 + ni * 16 + l15) * 128 + cswz);
      #pragma unroll
      for (int mi = 0; mi < 4; ++mi)
        #pragma unroll
        for (int ni = 0; ni < 2; ++ni)
          acc[mi][ni] = __builtin_amdgcn_mfma_f32_16x16x32_bf16(a[mi], b[ni], acc[mi][ni], 0, 0, 0);
    }
  }

  #pragma unroll
  for (int mi = 0; mi < 4; ++mi)
    #pragma unroll
    for (int r = 0; r < 4; ++r) {
      int dh = mi * 16 + lg * 4 + r;
      float bias = bkqv[h * E_ + 2048 + dh];
      #pragma unroll
      for (int ni = 0; ni < 2; ++ni) {
        int nn = nt * 128 + w * 32 + ni * 16 + l15;
        int b = nn >> 10, n = nn & (N_ - 1);
        int bh = b * H_ + h;
        Vt[((size_t)bh * DH_ + dh) * N_ + n] = (bf16_t)(acc[mi][ni][r] + bias);
      }
    }
}

// ---------------------------------------------------------------------------
// 256x256xK=1024 pipelined core — PROVEN r9/r12 version (reverted from r13).
// 4 phases/K-tile, one barrier per phase, counted vmcnt(8) (never 0 in main
// loop), T2 swizzle, T5 setprio. Staging issue points race-free (see r7/r8).
// ---------------------------------------------------------------------------
#define WV8 asm volatile("s_waitcnt vmcnt(8)" ::: "memory")
#define WV2 asm volatile("s_waitcnt vmcnt(2)" ::: "memory")
#define WV0 asm volatile("s_waitcnt vmcnt(0)" ::: "memory")
#define WNONE

__device__ __forceinline__ void mm256_core(const bf16_t* __restrict__ Ag,
                                           const bf16_t* __restrict__ Bg,
                                           bf16_t* lds, f32x4 (&acc)[8][4]) {
  char* Asp = (char*)lds;
  char* Bsp = (char*)lds + 65536;
  const int t = threadIdx.x;
  const int w = t >> 6, l = t & 63, l15 = l & 15, lg = l >> 4;
  const int wm = w >> 2, wn = w & 3;

  const int lr = l >> 3;
  const int scol = ((l & 7) ^ lr) << 3;
  const bf16_t* bS = Bg + (size_t)(w * 8 + lr) * 1024 + scol;
  const int idxA = w * 8 + lr;
  const bf16_t* aS0 = Ag + (size_t)((idxA >> 4) * 32 + (idxA & 15)) * 1024 + scol;
  const bf16_t* aS1 = aS0 + (size_t)128 * 1024;

#define STG_B(bufi, hh, ktv)                                                   \
  do {                                                                         \
    gload_lds16(bS + (size_t)((hh) * 128) * 1024 + (ktv) * 64,                 \
                Bsp + (bufi) * 32768 + (hh) * 16384 + w * 1024);               \
    gload_lds16(bS + (size_t)((hh) * 128 + 64) * 1024 + (ktv) * 64,            \
                Bsp + (bufi) * 32768 + (hh) * 16384 + 8192 + w * 1024);        \
  } while (0)
#define STG_A(bufi, hh, ktv)                                                   \
  do {                                                                         \
    gload_lds16(aS0 + (size_t)((hh) * 16) * 1024 + (ktv) * 64,                 \
                Asp + (bufi) * 32768 + (hh) * 16384 + w * 1024);               \
    gload_lds16(aS1 + (size_t)((hh) * 16) * 1024 + (ktv) * 64,                 \
                Asp + (bufi) * 32768 + (hh) * 16384 + 8192 + w * 1024);        \
  } while (0)

  STG_B(0, 0, 0); STG_B(0, 1, 0);
  STG_A(0, 0, 0); STG_A(0, 1, 0);
  STG_B(1, 0, 1); STG_B(1, 1, 1);
  STG_A(1, 0, 1);
  WV8;
  __builtin_amdgcn_s_barrier();

  const int rswz = (l15 & 7) << 4;
  const int bro = ((wn & 1) * 64 + l15) * 128;

#define TILE_STEP(KT, SA1, SB, SA0, W1, W3)                                    \
  {                                                                            \
    const int kb_ = (KT) & 1;                                                  \
    const char* Ab = Asp + kb_ * 32768;                                        \
    const char* Bb = Bsp + kb_ * 32768 + (wn >> 1) * 16384;                    \
    bf16x8 b0[4], b1[4];                                                       \
    {                                                                          \
      const int cs = (lg * 16) ^ rswz;                                         \
      bf16x8 a[4];                                                             \
      _Pragma("unroll") for (int ni = 0; ni < 4; ++ni)                         \
        b0[ni] = *(const bf16x8*)(Bb + bro + ni * 2048 + cs);                  \
      _Pragma("unroll") for (int q = 0; q < 4; ++q)                            \
        a[q] = *(const bf16x8*)(Ab + ((wm * 4 + q) * 16 + l15) * 128 + cs);    \
      if (SA1) STG_A(((KT) + 1) & 1, 1, (KT) + 1);                             \
      asm volatile("s_waitcnt lgkmcnt(0)" ::: "memory");                       \
      __builtin_amdgcn_s_setprio(1);                                           \
      _Pragma("unroll") for (int q = 0; q < 4; ++q)                            \
        _Pragma("unroll") for (int ni = 0; ni < 4; ++ni)                       \
          acc[2 * q][ni] = __builtin_amdgcn_mfma_f32_16x16x32_bf16(            \
              a[q], b0[ni], acc[2 * q][ni], 0, 0, 0);                          \
      __builtin_amdgcn_s_setprio(0);                                           \
      __builtin_amdgcn_s_barrier();                                            \
    }                                                                          \
    {                                                                          \
      const int cs = (64 + lg * 16) ^ rswz;                                    \
      bf16x8 a[4];                                                             \
      _Pragma("unroll") for (int ni = 0; ni < 4; ++ni)                         \
        b1[ni] = *(const bf16x8*)(Bb + bro + ni * 2048 + cs);                  \
      _Pragma("unroll") for (int q = 0; q < 4; ++q)                            \
        a[q] = *(const bf16x8*)(Ab + ((wm * 4 + q) * 16 + l15) * 128 + cs);    \
      asm volatile("s_waitcnt lgkmcnt(0)" ::: "memory");                       \
      __builtin_amdgcn_s_setprio(1);                                           \
      _Pragma("unroll") for (int q = 0; q < 4; ++q)                            \
        _Pragma("unroll") for (int ni = 0; ni < 4; ++ni)                       \
          acc[2 * q][ni] = __builtin_amdgcn_mfma_f32_16x16x32_bf16(            \
              a[q], b1[ni], acc[2 * q][ni], 0, 0, 0);                          \
      __builtin_amdgcn_s_setprio(0);                                           \
      W1;                                                                      \
      __builtin_amdgcn_s_barrier();                                            \
    }                                                                          \
    {                                                                          \
      const int cs = (lg * 16) ^ rswz;                                         \
      bf16x8 a[4];                                                             \
      _Pragma("unroll") for (int q = 0; q < 4; ++q)                            \
        a[q] = *(const bf16x8*)(Ab + 16384 + ((wm * 4 + q) * 16 + l15) * 128 + cs); \
      if (SB) { STG_B((KT) & 1, 0, (KT) + 2); STG_B((KT) & 1, 1, (KT) + 2); }  \
      asm volatile("s_waitcnt lgkmcnt(0)" ::: "memory");                       \
      __builtin_amdgcn_s_setprio(1);                                           \
      _Pragma("unroll") for (int q = 0; q < 4; ++q)                            \
        _Pragma("unroll") for (int ni = 0; ni < 4; ++ni)                       \
          acc[2 * q + 1][ni] = __builtin_amdgcn_mfma_f32_16x16x32_bf16(        \
              a[q], b0[ni], acc[2 * q + 1][ni], 0, 0, 0);                      \
      __builtin_amdgcn_s_setprio(0);                                           \
      __builtin_amdgcn_s_barrier();                                            \
    }                                                                          \
    {                                                                          \
      const int cs = (64 + lg * 16) ^ rswz;                                    \
      bf16x8 a[4];                                                             \
      _Pragma("unroll") for (int q = 0; q < 4; ++q)                            \
        a[q] = *(const bf16x8*)(Ab + 16384 + ((wm * 4 + q) * 16 + l15) * 128 + cs); \
      if (SA0) STG_A((KT) & 1, 0, (KT) + 2);                                   \
      asm volatile("s_waitcnt lgkmcnt(0)" ::: "memory");                       \
      __builtin_amdgcn_s_setprio(1);                                           \
      _Pragma("unroll") for (int q = 0; q < 4; ++q)                            \
        _Pragma("unroll") for (int ni = 0; ni < 4; ++ni)                       \
          acc[2 * q + 1][ni] = __builtin_amdgcn_mfma_f32_16x16x32_bf16(        \
              a[q], b1[ni], acc[2 * q + 1][ni], 0, 0, 0);                      \
      __builtin_amdgcn_s_setprio(0);                                           \
      W3;                                                                      \
      __builtin_amdgcn_s_barrier();                                            \
    }                                                                          \
  }

  for (int kt = 0; kt < 14; ++kt) TILE_STEP(kt, 1, 1, 1, WV8, WV8);
  TILE_STEP(14, 1, 0, 0, WV8, WV2);
  TILE_STEP(15, 0, 0, 0, WV0, WNONE);

#undef TILE_STEP
#undef STG_A
#undef STG_B
}

__device__ __forceinline__ int xchunk4(int colf) {
  int c = colf >> 2;
  return ((c ^ (c >> 3)) << 2) | (colf & 3);
}

__device__ __forceinline__ void epi256_bf16(f32x4 (&acc)[8][4], bf16_t* lds,
                                            bf16_t* dst, int rowstride) {
  const int t = threadIdx.x;
  const int l = t & 63, l15 = l & 15, lg = l >> 4;
  const int w = t >> 6;
  const int wm = w >> 2, wn = w & 3;
  float* Ct = (float*)lds;   // [64][258]
  const int cpair = t & 31;
  const int p0 = xchunk4(cpair * 8);
  const int p1 = xchunk4(cpair * 8 + 4);
  #pragma unroll
  for (int s = 0; s < 4; ++s) {
    __syncthreads();
    #pragma unroll
    for (int m2 = 0; m2 < 2; ++m2)
      #pragma unroll
      for (int ni = 0; ni < 4; ++ni)
        #pragma unroll
        for (int r = 0; r < 4; ++r)
          Ct[(wm * 32 + m2 * 16 + lg * 4 + r) * 258 +
             xchunk4(wn * 64 + ni * 16 + l15)] = acc[2 * s + m2][ni][r];
    __syncthreads();
    #pragma unroll
    for (int it = 0; it < 4; ++it) {
      int row64 = (t >> 5) + it * 16;
      int wmq = row64 >> 5, m2q = (row64 >> 4) & 1, r16 = row64 & 15;
      int c8 = cpair * 8;
      const float* r0 = &Ct[row64 * 258 + p0];
      const float* r1 = &Ct[row64 * 258 + p1];
      bf16x8 o = {(bf16_t)r0[0], (bf16_t)r0[1], (bf16_t)r0[2], (bf16_t)r0[3],
                  (bf16_t)r1[0], (bf16_t)r1[1], (bf16_t)r1[2], (bf16_t)r1[3]};
      int lrow = wmq * 128 + (2 * s + m2q) * 16 + r16;
      *(bf16x8*)(dst + (size_t)lrow * rowstride + c8) = o;
    }
  }
}

// ---------------------------------------------------------------------------
// m_gemm: MT[h][d'][d] = sum_e Wk[d'][e] Wq[d][e]
// ---------------------------------------------------------------------------
__global__ __launch_bounds__(512)
void m_gemm(const bf16_t* __restrict__ Wkb, const bf16_t* __restrict__ Wqb,
            bf16_t* __restrict__ MT) {
  __shared__ bf16_t lds[65536];
  const int bid = blockIdx.x;          // 256 blocks
  const int mb = bid & 3, nb = (bid >> 2) & 3, h = bid >> 4;
  f32x4 acc[8][4] = {};
  mm256_core(Wkb + ((size_t)h * 1024 + mb * 256) * 1024,
             Wqb + ((size_t)h * 1024 + nb * 256) * 1024, lds, acc);
  epi256_bf16(acc, lds,
              MT + ((size_t)h * 1024 + mb * 256) * 1024 + nb * 256, 1024);
}

// ---------------------------------------------------------------------------
// t_gemm: T[bh][i][d'] = sum_d x[b][i][d] MT[h][d'][d]
// ---------------------------------------------------------------------------
__global__ __launch_bounds__(512)
void t_gemm(const bf16_t* __restrict__ xb, const bf16_t* __restrict__ MT,
            bf16_t* __restrict__ T) {
  __shared__ bf16_t lds[65536];
  const int bid = blockIdx.x;                      // 1024 blocks
  const int lid = (bid & 7) * 128 + (bid >> 3);    // XCD swizzle
  const int mb = lid & 15, nb = (lid >> 4) & 3, h = lid >> 6;
  f32x4 acc[8][4] = {};
  mm256_core(xb + (size_t)mb * 256 * 1024,
             MT + ((size_t)h * 1024 + nb * 256) * 1024, lds, acc);
  const int b = mb >> 2;
  const int bh = b * 16 + h;
  epi256_bf16(acc, lds,
              T + (size_t)bh * 1024 * 1024 + (size_t)((mb & 3) * 256) * 1024 +
                  nb * 256, 1024);
}

// ---------------------------------------------------------------------------
// s_gemm256: S = (T.x^T + u_i + v_j) * SCALE, lower-triangle 256^2 tiles,
// all 64 bh (640 blocks); bf16 out.
// ---------------------------------------------------------------------------
__global__ __launch_bounds__(512)
void s_gemm256(const bf16_t* __restrict__ T, const bf16_t* __restrict__ xb,
               const float* __restrict__ u, const float* __restrict__ v,
               bf16_t* __restrict__ Sg) {
  __shared__ bf16_t lds[65536];
  const int bid = blockIdx.x;                 // 0..639
  const int lid = (bid & 7) * 80 + (bid >> 3);
  const int idx = lid % 10;
  const int bh = lid / 10;
  const int bb = bh >> 4;
  int qt = 0;
  while ((qt + 1) * (qt + 2) / 2 <= idx) ++qt;
  const int kt = idx - qt * (qt + 1) / 2;

  f32x4 acc[8][4] = {};
  mm256_core(T + (size_t)bh * 1024 * 1024 + (size_t)qt * 256 * 1024,
             xb + (size_t)bb * 1024 * 1024 + (size_t)kt * 256 * 1024, lds, acc);

  const int t = threadIdx.x;
  const int w = t >> 6, l = t & 63, l15 = l & 15, lg = l >> 4;
  const int wm = w >> 2, wn = w & 3;
  const float SCALE = 0.045084220027780106f;   // log2(e)/sqrt(1024)
  bf16_t* So = Sg + (((size_t)bh * 10 + idx) << 16);

  const float* ubh = u + (size_t)bh * 1024 + qt * 256;
  const float* vbh = v + (size_t)bh * 1024 + kt * 256;
  float vv[4];
  #pragma unroll
  for (int ni = 0; ni < 4; ++ni) vv[ni] = vbh[wn * 64 + ni * 16 + l15];

  #pragma unroll
  for (int mi = 0; mi < 8; ++mi)
    #pragma unroll
    for (int r = 0; r < 4; ++r) {
      int rl = wm * 128 + mi * 16 + lg * 4 + r;
      float uu = ubh[rl];
      #pragma unroll
      for (int ni = 0; ni < 4; ++ni) {
        int cl = wn * 64 + ni * 16 + l15;
        float z = (acc[mi][ni][r] + uu + vv[ni]) * SCALE;
        if (kt * 256 + cl > qt * 256 + rl) z = -1e30f;
        acc[mi][ni][r] = z;
      }
    }

  epi256_bf16(acc, lds, So, 256);
}

// ---------------------------------------------------------------------------
// softmax + P.V (bf16 S)
// ---------------------------------------------------------------------------
__global__ __launch_bounds__(256)
void softmax_pv(const bf16_t* __restrict__ Sg, const bf16_t* __restrict__ Vt,
                bf16_t* __restrict__ sa) {
  const int qt = blockIdx.x;   // 0..15
  const int bh = blockIdx.y;   // 0..63
  const int t = threadIdx.x;
  const int w = t >> 6, l = t & 63, l15 = l & 15, lg = l >> 4;
  const int b = bh >> 4, h = bh & 15;

  const int qrow = qt * 64 + w * 16 + l15;
  const int qt8 = qt >> 2;
  const bf16_t* Sbh = Sg + (((size_t)bh * 10) << 16);
  const bf16_t* Vh = Vt + (size_t)bh * DH_ * N_;

  f32x4 accO[4] = {};
  float m = -1e30f, lsum = 0.f;

  for (int j = 0; j <= qt; ++j) {
    const int jb = j * 64;
    const int tid = qt8 * (qt8 + 1) / 2 + (j >> 2);
    const bf16_t* Srow = Sbh + ((size_t)tid << 16) +
                         (size_t)(qrow & 255) * 256 + (jb & 255);

    bf16x8 h0 = *(const bf16x8*)(Srow + lg * 8);
    bf16x8 h1 = *(const bf16x8*)(Srow + 32 + lg * 8);
    float z[16];
    #pragma unroll
    for (int i = 0; i < 8; ++i) z[i] = (float)h0[i];
    #pragma unroll
    for (int i = 0; i < 8; ++i) z[8 + i] = (float)h1[i];

    float zm = z[0];
    #pragma unroll
    for (int i = 1; i < 16; ++i) zm = fmaxf(zm, z[i]);
    zm = fmaxf(zm, __shfl_xor(zm, 16));
    zm = fmaxf(zm, __shfl_xor(zm, 32));

    float mnew = fmaxf(m, zm);
    float scl = exp2f(m - mnew);
    m = mnew;

    float p[16];
    #pragma unroll
    for (int i = 0; i < 16; ++i) p[i] = exp2f(z[i] - mnew);

    float rs = 0.f;
    #pragma unroll
    for (int i = 0; i < 16; ++i) rs += p[i];
    rs += __shfl_xor(rs, 16);
    rs += __shfl_xor(rs, 32);
    lsum = lsum * scl + rs;

    float sclO[4];
    #pragma unroll
    for (int r = 0; r < 4; ++r) sclO[r] = __shfl(scl, lg * 4 + r);
    #pragma unroll
    for (int db = 0; db < 4; ++db)
      #pragma unroll
      for (int r = 0; r < 4; ++r) accO[db][r] *= sclO[r];

    bf16x8 pa0 = {(bf16_t)p[0], (bf16_t)p[1], (bf16_t)p[2], (bf16_t)p[3],
                  (bf16_t)p[4], (bf16_t)p[5], (bf16_t)p[6], (bf16_t)p[7]};
    bf16x8 pa1 = {(bf16_t)p[8], (bf16_t)p[9], (bf16_t)p[10], (bf16_t)p[11],
                  (bf16_t)p[12], (bf16_t)p[13], (bf16_t)p[14], (bf16_t)p[15]};

    #pragma unroll
    for (int db = 0; db < 4; ++db) {
      const bf16_t* vp = Vh + (size_t)(db * 16 + l15) * N_ + jb;
      bf16x8 vb0 = *(const bf16x8*)(vp + lg * 8);
      bf16x8 vb1 = *(const bf16x8*)(vp + 32 + lg * 8);
      accO[db] = __builtin_amdgcn_mfma_f32_16x16x32_bf16(pa0, vb0, accO[db], 0, 0, 0);
      accO[db] = __builtin_amdgcn_mfma_f32_16x16x32_bf16(pa1, vb1, accO[db], 0, 0, 0);
    }
  }

  float lO[4];
  #pragma unroll
  for (int r = 0; r < 4; ++r) lO[r] = __shfl(lsum, lg * 4 + r);

  #pragma unroll
  for (int db = 0; db < 4; ++db)
    #pragma unroll
    for (int r = 0; r < 4; ++r) {
      int row = qt * 64 + w * 16 + lg * 4 + r;
      int col = h * DH_ + db * 16 + l15;
      sa[((size_t)b * N_ + row) * D_ + col] = (bf16_t)(accO[db][r] / lO[r]);
    }
}

// ---------------------------------------------------------------------------
// out_gemm (m97 128^2 structure, fp32 out)
// ---------------------------------------------------------------------------
__global__ __launch_bounds__(256)
void out_gemm(const bf16_t* __restrict__ A, const bf16_t* __restrict__ Bt,
              const float* __restrict__ bp, float* __restrict__ out) {
  const int mb = blockIdx.x, nb = blockIdx.y;
  const int t = threadIdx.x;
  const int w = t >> 6, l = t & 63, l15 = l & 15, lg = l >> 4;
  const int wr = (w >> 1) * 64, wc = (w & 1) * 64;

  __shared__ bf16_t As[128 * 64];
  __shared__ bf16_t Bs[128 * 64];

  const int srow = w * 32 + (l >> 3);
  const int scol = (l & 7) * 8;
  const bf16_t* ag = A + (size_t)(mb * 128 + srow) * D_ + scol;
  const bf16_t* bg = Bt + (size_t)(nb * 128 + srow) * D_ + scol;
  char* asl = (char*)As + w * 4096;
  char* bsl = (char*)Bs + w * 4096;

  f32x4 acc[4][4] = {};

  for (int kb = 0; kb < 16; ++kb) {
    __syncthreads();
    #pragma unroll
    for (int i = 0; i < 4; ++i) {
      gload_lds16(ag + (size_t)i * 8 * D_ + kb * 64, asl + i * 1024);
      gload_lds16(bg + (size_t)i * 8 * D_ + kb * 64, bsl + i * 1024);
    }
    __syncthreads();
    #pragma unroll
    for (int ks = 0; ks < 2; ++ks) {
      bf16x8 a[4], b[4];
      #pragma unroll
      for (int mi = 0; mi < 4; ++mi)
        a[mi] = *(const bf16x8*)((const char*)As + (wr + mi * 16 + l15) * 128 + ks * 64 + lg * 16);
      #pragma unroll
      for (int ni = 0; ni < 4; ++ni)
        b[ni] = *(const bf16x8*)((const char*)Bs + (wc + ni * 16 + l15) * 128 + ks * 64 + lg * 16);
      #pragma unroll
      for (int mi = 0; mi < 4; ++mi)
        #pragma unroll
        for (int ni = 0; ni < 4; ++ni)
          acc[mi][ni] = __builtin_amdgcn_mfma_f32_16x16x32_bf16(a[mi], b[ni], acc[mi][ni], 0, 0, 0);
    }
  }

  #pragma unroll
  for (int ni = 0; ni < 4; ++ni) {
    int e = nb * 128 + wc + ni * 16 + l15;
    float bias = bp[e];
    #pragma unroll
    for (int mi = 0; mi < 4; ++mi)
      #pragma unroll
      for (int r = 0; r < 4; ++r) {
        int grow = mb * 128 + wr + mi * 16 + lg * 4 + r;
        out[(size_t)grow * D_ + e] = acc[mi][ni][r] + bias;
      }
  }
}

// ---------------------------------------------------------------------------
extern "C" void kernel_launch(void* const* d_in, const int* in_sizes, int n_in,
                              void* d_out, int out_size, void* d_ws, size_t ws_size,
                              hipStream_t stream) {
  const float* x    = (const float*)d_in[0];
  const float* Wkqv = (const float*)d_in[1];
  const float* bkqv = (const float*)d_in[2];
  const float* Wp   = (const float*)d_in[3];
  const float* bp   = (const float*)d_in[4];
  float* out = (float*)d_out;
  char* ws = (char*)d_ws;

  const size_t MB = 1 << 20;
  bf16_t* xb   = (bf16_t*)(ws);              //   8 MiB
  bf16_t* sa   = (bf16_t*)(ws + 8 * MB);     //   8 MiB
  bf16_t* Wpt  = (bf16_t*)(ws + 16 * MB);    //   2 MiB
  bf16_t* Vt   = (bf16_t*)(ws + 18 * MB);    //   8 MiB
  bf16_t* Wvt  = (bf16_t*)(ws + 26 * MB);    //   2 MiB
  bf16_t* MT   = (bf16_t*)(ws + 28 * MB);    //  32 MiB
  bf16_t* T    = (bf16_t*)(ws + 60 * MB);    // 128 MiB
  bf16_t* Wqb  = (bf16_t*)(ws + 188 * MB);   //  32 MiB (dead after m_gemm)
  bf16_t* Wkb  = (bf16_t*)(ws + 220 * MB);   //  32 MiB (dead after m_gemm)
  bf16_t* Sg   = (bf16_t*)(ws + 188 * MB);   //  80 MiB (reuses Wqb/Wkb)
  float*  u    = (float*) (ws + 268 * MB);               // 256 KiB
  float*  v    = (float*) (ws + 268 * MB + 256 * 1024);  // 256 KiB
  float*  wqbk = (float*) (ws + 268 * MB + 512 * 1024);  // 64 KiB
  float*  wkbq = (float*) (ws + 268 * MB + 576 * 1024);  // 64 KiB
  float*  bqk  = (float*) (ws + 268 * MB + 640 * 1024);  // 64 B
  // top < 269 MiB < proven-safe 285,212,672 B

  hipLaunchKernelGGL(prep_all, dim3(4112), dim3(256), 0, stream,
                     x, Wp, Wkqv, bkqv, xb, Wpt, Wvt, bqk,
                     Wqb, Wkb, wqbk, wkbq);
  hipLaunchKernelGGL(uv_v, dim3(1536), dim3(256), 0, stream,
                     x, bqk, wqbk, wkbq, u, v, xb, Wvt, bkqv, Vt);
  hipLaunchKernelGGL(m_gemm, dim3(256), dim3(512), 0, stream, Wkb, Wqb, MT);
  hipLaunchKernelGGL(t_gemm, dim3(1024), dim3(512), 0, stream, xb, MT, T);
  hipLaunchKernelGGL(s_gemm256, dim3(640), dim3(512), 0, stream,
                     T, xb, u, v, Sg);
  hipLaunchKernelGGL(softmax_pv, dim3(16, 64), dim3(256), 0, stream,
                     Sg, Vt, sa);
  hipLaunchKernelGGL(out_gemm, dim3(32, 8), dim3(256), 0, stream,
                     sa, Wpt, bp, out);
}

// Round 15
// 449.877 us; speedup vs baseline: 1.0675x; 1.0069x over previous
//
#include <hip/hip_runtime.h>
#include <hip/hip_bf16.h>

#define B_ 4
#define N_ 1024
#define D_ 1024
#define H_ 16
#define DH_ 64
#define E_ 2112
#define ROWS_ 4096

typedef __bf16 bf16_t;
typedef bf16_t bf16x4 __attribute__((ext_vector_type(4)));
typedef bf16_t bf16x8 __attribute__((ext_vector_type(8)));
typedef float f32x4 __attribute__((ext_vector_type(4)));

__device__ __forceinline__ void gload_lds16(const void* g, void* l) {
  __builtin_amdgcn_global_load_lds(
      (const __attribute__((address_space(1))) void*)g,
      (__attribute__((address_space(3))) void*)l, 16, 0, 0);
}

// ---------------------------------------------------------------------------
// prep_all: flat grid merging 5 independent prep stages.
//  [0,1024):    conv_x   x fp32 -> xb bf16
//  [1024,2048): conv_wp  Wp[k][n] -> Wpt[n][k] bf16
//  [2048,3072): conv_wv  W[h][d][2048+dh] -> Wvt[h][dh][d] bf16
//  [3072,3088): bqk[h] = bq . bk
//  [3088,4112): conv_wqk (Wkb/Wqb bf16 + bias-dot vectors wqbk/wkbq)
// ---------------------------------------------------------------------------
__global__ __launch_bounds__(256)
void prep_all(const float* __restrict__ x, const float* __restrict__ Wp,
              const float* __restrict__ W, const float* __restrict__ bkqv,
              bf16_t* __restrict__ xb, bf16_t* __restrict__ Wpt,
              bf16_t* __restrict__ Wvt, float* __restrict__ bqk,
              bf16_t* __restrict__ Wqb, bf16_t* __restrict__ Wkb,
              float* __restrict__ wqbk, float* __restrict__ wkbq) {
  __shared__ float smem[2592];
  const int bid = blockIdx.x;
  const int t = threadIdx.x;
  if (bid < 1024) {
    const int n4 = ROWS_ * D_ / 4;
    for (int i = bid * 256 + t; i < n4; i += 1024 * 256) {
      float4 v = ((const float4*)x)[i];
      bf16x4 o = {(bf16_t)v.x, (bf16_t)v.y, (bf16_t)v.z, (bf16_t)v.w};
      ((bf16x4*)xb)[i] = o;
    }
  } else if (bid < 2048) {
    const int id = bid - 1024;
    const int nt = id & 31, kt = id >> 5;
    const int tx = t & 31, ty = t >> 5;
    #pragma unroll
    for (int rr = 0; rr < 4; ++rr)
      smem[(rr * 8 + ty) * 33 + tx] =
          Wp[(size_t)(kt * 32 + rr * 8 + ty) * D_ + nt * 32 + tx];
    __syncthreads();
    #pragma unroll
    for (int rr = 0; rr < 4; ++rr)
      Wpt[(size_t)(nt * 32 + rr * 8 + ty) * D_ + kt * 32 + tx] =
          (bf16_t)smem[tx * 33 + rr * 8 + ty];
  } else if (bid < 3072) {
    const int id = bid - 2048;
    const int et = id & 1, dt = (id >> 1) & 31, h = id >> 6;
    const int tx = t & 31, ty = t >> 5;
    const float* Wh = W + (size_t)h * D_ * E_;
    #pragma unroll
    for (int rr = 0; rr < 4; ++rr) {
      int d = dt * 32 + rr * 8 + ty;
      int dh = et * 32 + tx;
      smem[(rr * 8 + ty) * 33 + tx] = Wh[(size_t)d * E_ + 2048 + dh];
    }
    __syncthreads();
    bf16_t* Wvo = Wvt + (size_t)h * DH_ * D_;
    #pragma unroll
    for (int rr = 0; rr < 4; ++rr) {
      int dh = et * 32 + rr * 8 + ty;
      int d = dt * 32 + tx;
      Wvo[(size_t)dh * D_ + d] = (bf16_t)smem[tx * 33 + rr * 8 + ty];
    }
  } else if (bid < 3088) {
    const int h = bid - 3072;
    const float* bk = bkqv + h * E_;
    const float* bq = bk + 1024;
    float4 a = *(const float4*)(bk + t * 4);
    float4 b = *(const float4*)(bq + t * 4);
    smem[t] = a.x * b.x + a.y * b.y + a.z * b.z + a.w * b.w;
    __syncthreads();
    for (int st = 128; st > 0; st >>= 1) {
      if (t < st) smem[t] += smem[t + st];
      __syncthreads();
    }
    if (t == 0) bqk[h] = smem[0];
  } else {
    const int id = bid - 3088;
    const int db = id & 63, h = id >> 6;
    const float* Wh = W + (size_t)h * D_ * E_;
    float* bkL = smem;            // [1024]
    float* bqL = smem + 1024;     // [1024]
    float* red = smem + 2048;     // [2][272]
    for (int i = t; i < 1024; i += 256) {
      bkL[i] = bkqv[h * E_ + i];
      bqL[i] = bkqv[h * E_ + 1024 + i];
    }
    __syncthreads();
    const int rt = t >> 4, ct = t & 15;
    const int d = db * 16 + rt;
    const float* rowp = Wh + (size_t)d * E_;
    float pk = 0.f, pq = 0.f;
    #pragma unroll
    for (int j = 0; j < 16; ++j) {
      int e4 = (ct + j * 16) * 4;
      float4 vk = *(const float4*)(rowp + e4);
      float4 vq = *(const float4*)(rowp + 1024 + e4);
      bf16x4 ok = {(bf16_t)vk.x, (bf16_t)vk.y, (bf16_t)vk.z, (bf16_t)vk.w};
      bf16x4 oq = {(bf16_t)vq.x, (bf16_t)vq.y, (bf16_t)vq.z, (bf16_t)vq.w};
      *(bf16x4*)(Wkb + ((size_t)h * 1024 + d) * 1024 + e4) = ok;
      *(bf16x4*)(Wqb + ((size_t)h * 1024 + d) * 1024 + e4) = oq;
      pk += vk.x * bqL[e4] + vk.y * bqL[e4 + 1] + vk.z * bqL[e4 + 2] + vk.w * bqL[e4 + 3];
      pq += vq.x * bkL[e4] + vq.y * bkL[e4 + 1] + vq.z * bkL[e4 + 2] + vq.w * bkL[e4 + 3];
    }
    red[0 * 272 + rt * 17 + ct] = pk;
    red[1 * 272 + rt * 17 + ct] = pq;
    __syncthreads();
    if (t < 32) {
      int which = t >> 4, r = t & 15;
      float s = 0.f;
      #pragma unroll
      for (int c2 = 0; c2 < 16; ++c2) s += red[which * 272 + r * 17 + c2];
      if (which == 0) wkbq[h * 1024 + db * 16 + r] = s;
      else            wqbk[h * 1024 + db * 16 + r] = s;
    }
  }
}

// ---------------------------------------------------------------------------
// uv_v: merged uv_kernel [0,1024) + v_gemm [1024,1536).
// ---------------------------------------------------------------------------
__global__ __launch_bounds__(256)
void uv_v(const float* __restrict__ x, const float* __restrict__ bqk,
          const float* __restrict__ wqbk, const float* __restrict__ wkbq,
          float* __restrict__ u, float* __restrict__ v,
          const bf16_t* __restrict__ xb, const bf16_t* __restrict__ Wvt,
          const float* __restrict__ bkqv, bf16_t* __restrict__ Vt) {
  __shared__ bf16_t As2[64 * 64];
  __shared__ bf16_t Bs2[128 * 64];
  const int bid = blockIdx.x;
  const int t = threadIdx.x;
  if (bid < 1024) {
    const int w = t >> 6, l = t & 63;
    const int rg = bid * 4 + w;
    const int b = rg >> 10, n = rg & 1023;
    const float* xr = x + (size_t)rg * 1024 + l * 16;
    float4 xv0 = *(const float4*)(xr);
    float4 xv1 = *(const float4*)(xr + 4);
    float4 xv2 = *(const float4*)(xr + 8);
    float4 xv3 = *(const float4*)(xr + 12);
    #pragma unroll
    for (int h = 0; h < 16; ++h) {
      const float* wq = wqbk + h * 1024 + l * 16;
      const float* wk = wkbq + h * 1024 + l * 16;
      float4 q0 = *(const float4*)(wq);
      float4 q1 = *(const float4*)(wq + 4);
      float4 q2 = *(const float4*)(wq + 8);
      float4 q3 = *(const float4*)(wq + 12);
      float4 k0 = *(const float4*)(wk);
      float4 k1 = *(const float4*)(wk + 4);
      float4 k2 = *(const float4*)(wk + 8);
      float4 k3 = *(const float4*)(wk + 12);
      float au = xv0.x * q0.x + xv0.y * q0.y + xv0.z * q0.z + xv0.w * q0.w
               + xv1.x * q1.x + xv1.y * q1.y + xv1.z * q1.z + xv1.w * q1.w
               + xv2.x * q2.x + xv2.y * q2.y + xv2.z * q2.z + xv2.w * q2.w
               + xv3.x * q3.x + xv3.y * q3.y + xv3.z * q3.z + xv3.w * q3.w;
      float av = xv0.x * k0.x + xv0.y * k0.y + xv0.z * k0.z + xv0.w * k0.w
               + xv1.x * k1.x + xv1.y * k1.y + xv1.z * k1.z + xv1.w * k1.w
               + xv2.x * k2.x + xv2.y * k2.y + xv2.z * k2.z + xv2.w * k2.w
               + xv3.x * k3.x + xv3.y * k3.y + xv3.z * k3.z + xv3.w * k3.w;
      #pragma unroll
      for (int s = 1; s < 64; s <<= 1) {
        au += __shfl_xor(au, s);
        av += __shfl_xor(av, s);
      }
      if (l == 0) {
        int bh = b * 16 + h;
        u[(size_t)bh * 1024 + n] = au + bqk[h];
        v[(size_t)bh * 1024 + n] = av;
      }
    }
    return;
  }
  // ---- v_gemm part
  const int id = bid - 1024;
  const int nt = id & 31, h = id >> 5;
  const int w = t >> 6, l = t & 63, l15 = l & 15, lg = l >> 4;
  const bf16_t* Wvh = Wvt + (size_t)h * DH_ * D_;
  const bf16_t* Bn = xb + (size_t)nt * 128 * D_;

  f32x4 acc[4][2] = {};
  const int rswz = (l15 & 7) << 4;

  for (int kb = 0; kb < 16; ++kb) {
    __syncthreads();
    #pragma unroll
    for (int i = 0; i < 2; ++i) {
      int idx = t + i * 256;
      int row = idx >> 3, c = idx & 7;
      gload_lds16(Wvh + (size_t)row * D_ + kb * 64 + ((c ^ (row & 7)) << 3),
                  (char*)As2 + idx * 16);
    }
    #pragma unroll
    for (int i = 0; i < 4; ++i) {
      int idx = t + i * 256;
      int row = idx >> 3, c = idx & 7;
      gload_lds16(Bn + (size_t)row * D_ + kb * 64 + ((c ^ (row & 7)) << 3),
                  (char*)Bs2 + idx * 16);
    }
    __syncthreads();
    #pragma unroll
    for (int ks = 0; ks < 2; ++ks) {
      const int cswz = (ks * 64 + lg * 16) ^ rswz;
      bf16x8 a[4], b[2];
      #pragma unroll
      for (int mi = 0; mi < 4; ++mi)
        a[mi] = *(const bf16x8*)((const char*)As2 + (mi * 16 + l15) * 128 + cswz);
      #pragma unroll
      for (int ni = 0; ni < 2; ++ni)
        b[ni] = *(const bf16x8*)((const char*)Bs2 + (w * 32 + ni * 16 + l15) * 128 + cswz);
      #pragma unroll
      for (int mi = 0; mi < 4; ++mi)
        #pragma unroll
        for (int ni = 0; ni < 2; ++ni)
          acc[mi][ni] = __builtin_amdgcn_mfma_f32_16x16x32_bf16(a[mi], b[ni], acc[mi][ni], 0, 0, 0);
    }
  }

  #pragma unroll
  for (int mi = 0; mi < 4; ++mi)
    #pragma unroll
    for (int r = 0; r < 4; ++r) {
      int dh = mi * 16 + lg * 4 + r;
      float bias = bkqv[h * E_ + 2048 + dh];
      #pragma unroll
      for (int ni = 0; ni < 2; ++ni) {
        int nn = nt * 128 + w * 32 + ni * 16 + l15;
        int b = nn >> 10, n = nn & (N_ - 1);
        int bh = b * H_ + h;
        Vt[((size_t)bh * DH_ + dh) * N_ + n] = (bf16_t)(acc[mi][ni][r] + bias);
      }
    }
}

// ---------------------------------------------------------------------------
// 256x256xK=1024 pipelined core. Identical to r14 EXCEPT: the explicit
// "s_waitcnt lgkmcnt(0)" before each MFMA cluster is REMOVED — the compiler
// emits its own counted lgkmcnt per dependency (m97-verified behavior),
// letting the MFMA cluster start while the read tail drains. Correctness:
// every ds_read's value is consumed by an MFMA at or before the phase-end
// barrier, so the compiler's dependency waits retire all reads before the
// barrier; the staging-overwrite invariant (readers drained before STG to
// the same buffer) is unchanged.
// ---------------------------------------------------------------------------
#define WV8 asm volatile("s_waitcnt vmcnt(8)" ::: "memory")
#define WV2 asm volatile("s_waitcnt vmcnt(2)" ::: "memory")
#define WV0 asm volatile("s_waitcnt vmcnt(0)" ::: "memory")
#define WNONE

__device__ __forceinline__ void mm256_core(const bf16_t* __restrict__ Ag,
                                           const bf16_t* __restrict__ Bg,
                                           bf16_t* lds, f32x4 (&acc)[8][4]) {
  char* Asp = (char*)lds;
  char* Bsp = (char*)lds + 65536;
  const int t = threadIdx.x;
  const int w = t >> 6, l = t & 63, l15 = l & 15, lg = l >> 4;
  const int wm = w >> 2, wn = w & 3;

  const int lr = l >> 3;
  const int scol = ((l & 7) ^ lr) << 3;
  const bf16_t* bS = Bg + (size_t)(w * 8 + lr) * 1024 + scol;
  const int idxA = w * 8 + lr;
  const bf16_t* aS0 = Ag + (size_t)((idxA >> 4) * 32 + (idxA & 15)) * 1024 + scol;
  const bf16_t* aS1 = aS0 + (size_t)128 * 1024;

#define STG_B(bufi, hh, ktv)                                                   \
  do {                                                                         \
    gload_lds16(bS + (size_t)((hh) * 128) * 1024 + (ktv) * 64,                 \
                Bsp + (bufi) * 32768 + (hh) * 16384 + w * 1024);               \
    gload_lds16(bS + (size_t)((hh) * 128 + 64) * 1024 + (ktv) * 64,            \
                Bsp + (bufi) * 32768 + (hh) * 16384 + 8192 + w * 1024);        \
  } while (0)
#define STG_A(bufi, hh, ktv)                                                   \
  do {                                                                         \
    gload_lds16(aS0 + (size_t)((hh) * 16) * 1024 + (ktv) * 64,                 \
                Asp + (bufi) * 32768 + (hh) * 16384 + w * 1024);               \
    gload_lds16(aS1 + (size_t)((hh) * 16) * 1024 + (ktv) * 64,                 \
                Asp + (bufi) * 32768 + (hh) * 16384 + 8192 + w * 1024);        \
  } while (0)

  STG_B(0, 0, 0); STG_B(0, 1, 0);
  STG_A(0, 0, 0); STG_A(0, 1, 0);
  STG_B(1, 0, 1); STG_B(1, 1, 1);
  STG_A(1, 0, 1);
  WV8;
  __builtin_amdgcn_s_barrier();

  const int rswz = (l15 & 7) << 4;
  const int bro = ((wn & 1) * 64 + l15) * 128;

#define TILE_STEP(KT, SA1, SB, SA0, W1, W3)                                    \
  {                                                                            \
    const int kb_ = (KT) & 1;                                                  \
    const char* Ab = Asp + kb_ * 32768;                                        \
    const char* Bb = Bsp + kb_ * 32768 + (wn >> 1) * 16384;                    \
    bf16x8 b0[4], b1[4];                                                       \
    {                                                                          \
      const int cs = (lg * 16) ^ rswz;                                         \
      bf16x8 a[4];                                                             \
      _Pragma("unroll") for (int ni = 0; ni < 4; ++ni)                         \
        b0[ni] = *(const bf16x8*)(Bb + bro + ni * 2048 + cs);                  \
      _Pragma("unroll") for (int q = 0; q < 4; ++q)                            \
        a[q] = *(const bf16x8*)(Ab + ((wm * 4 + q) * 16 + l15) * 128 + cs);    \
      if (SA1) STG_A(((KT) + 1) & 1, 1, (KT) + 1);                             \
      __builtin_amdgcn_s_setprio(1);                                           \
      _Pragma("unroll") for (int q = 0; q < 4; ++q)                            \
        _Pragma("unroll") for (int ni = 0; ni < 4; ++ni)                       \
          acc[2 * q][ni] = __builtin_amdgcn_mfma_f32_16x16x32_bf16(            \
              a[q], b0[ni], acc[2 * q][ni], 0, 0, 0);                          \
      __builtin_amdgcn_s_setprio(0);                                           \
      __builtin_amdgcn_s_barrier();                                            \
    }                                                                          \
    {                                                                          \
      const int cs = (64 + lg * 16) ^ rswz;                                    \
      bf16x8 a[4];                                                             \
      _Pragma("unroll") for (int ni = 0; ni < 4; ++ni)                         \
        b1[ni] = *(const bf16x8*)(Bb + bro + ni * 2048 + cs);                  \
      _Pragma("unroll") for (int q = 0; q < 4; ++q)                            \
        a[q] = *(const bf16x8*)(Ab + ((wm * 4 + q) * 16 + l15) * 128 + cs);    \
      __builtin_amdgcn_s_setprio(1);                                           \
      _Pragma("unroll") for (int q = 0; q < 4; ++q)                            \
        _Pragma("unroll") for (int ni = 0; ni < 4; ++ni)                       \
          acc[2 * q][ni] = __builtin_amdgcn_mfma_f32_16x16x32_bf16(            \
              a[q], b1[ni], acc[2 * q][ni], 0, 0, 0);                          \
      __builtin_amdgcn_s_setprio(0);                                           \
      W1;                                                                      \
      __builtin_amdgcn_s_barrier();                                            \
    }                                                                          \
    {                                                                          \
      const int cs = (lg * 16) ^ rswz;                                         \
      bf16x8 a[4];                                                             \
      _Pragma("unroll") for (int q = 0; q < 4; ++q)                            \
        a[q] = *(const bf16x8*)(Ab + 16384 + ((wm * 4 + q) * 16 + l15) * 128 + cs); \
      if (SB) { STG_B((KT) & 1, 0, (KT) + 2); STG_B((KT) & 1, 1, (KT) + 2); }  \
      __builtin_amdgcn_s_setprio(1);                                           \
      _Pragma("unroll") for (int q = 0; q < 4; ++q)                            \
        _Pragma("unroll") for (int ni = 0; ni < 4; ++ni)                       \
          acc[2 * q + 1][ni] = __builtin_amdgcn_mfma_f32_16x16x32_bf16(        \
              a[q], b0[ni], acc[2 * q + 1][ni], 0, 0, 0);                      \
      __builtin_amdgcn_s_setprio(0);                                           \
      __builtin_amdgcn_s_barrier();                                            \
    }                                                                          \
    {                                                                          \
      const int cs = (64 + lg * 16) ^ rswz;                                    \
      bf16x8 a[4];                                                             \
      _Pragma("unroll") for (int q = 0; q < 4; ++q)                            \
        a[q] = *(const bf16x8*)(Ab + 16384 + ((wm * 4 + q) * 16 + l15) * 128 + cs); \
      if (SA0) STG_A((KT) & 1, 0, (KT) + 2);                                   \
      __builtin_amdgcn_s_setprio(1);                                           \
      _Pragma("unroll") for (int q = 0; q < 4; ++q)                            \
        _Pragma("unroll") for (int ni = 0; ni < 4; ++ni)                       \
          acc[2 * q + 1][ni] = __builtin_amdgcn_mfma_f32_16x16x32_bf16(        \
              a[q], b1[ni], acc[2 * q + 1][ni], 0, 0, 0);                      \
      __builtin_amdgcn_s_setprio(0);                                           \
      W3;                                                                      \
      __builtin_amdgcn_s_barrier();                                            \
    }                                                                          \
  }

  for (int kt = 0; kt < 14; ++kt) TILE_STEP(kt, 1, 1, 1, WV8, WV8);
  TILE_STEP(14, 1, 0, 0, WV8, WV2);
  TILE_STEP(15, 0, 0, 0, WV0, WNONE);

#undef TILE_STEP
#undef STG_A
#undef STG_B
}

__device__ __forceinline__ int xchunk4(int colf) {
  int c = colf >> 2;
  return ((c ^ (c >> 3)) << 2) | (colf & 3);
}

__device__ __forceinline__ void epi256_bf16(f32x4 (&acc)[8][4], bf16_t* lds,
                                            bf16_t* dst, int rowstride) {
  const int t = threadIdx.x;
  const int l = t & 63, l15 = l & 15, lg = l >> 4;
  const int w = t >> 6;
  const int wm = w >> 2, wn = w & 3;
  float* Ct = (float*)lds;   // [64][258]
  const int cpair = t & 31;
  const int p0 = xchunk4(cpair * 8);
  const int p1 = xchunk4(cpair * 8 + 4);
  #pragma unroll
  for (int s = 0; s < 4; ++s) {
    __syncthreads();
    #pragma unroll
    for (int m2 = 0; m2 < 2; ++m2)
      #pragma unroll
      for (int ni = 0; ni < 4; ++ni)
        #pragma unroll
        for (int r = 0; r < 4; ++r)
          Ct[(wm * 32 + m2 * 16 + lg * 4 + r) * 258 +
             xchunk4(wn * 64 + ni * 16 + l15)] = acc[2 * s + m2][ni][r];
    __syncthreads();
    #pragma unroll
    for (int it = 0; it < 4; ++it) {
      int row64 = (t >> 5) + it * 16;
      int wmq = row64 >> 5, m2q = (row64 >> 4) & 1, r16 = row64 & 15;
      int c8 = cpair * 8;
      const float* r0 = &Ct[row64 * 258 + p0];
      const float* r1 = &Ct[row64 * 258 + p1];
      bf16x8 o = {(bf16_t)r0[0], (bf16_t)r0[1], (bf16_t)r0[2], (bf16_t)r0[3],
                  (bf16_t)r1[0], (bf16_t)r1[1], (bf16_t)r1[2], (bf16_t)r1[3]};
      int lrow = wmq * 128 + (2 * s + m2q) * 16 + r16;
      *(bf16x8*)(dst + (size_t)lrow * rowstride + c8) = o;
    }
  }
}

// ---------------------------------------------------------------------------
// m_gemm: MT[h][d'][d] = sum_e Wk[d'][e] Wq[d][e]
// ---------------------------------------------------------------------------
__global__ __launch_bounds__(512)
void m_gemm(const bf16_t* __restrict__ Wkb, const bf16_t* __restrict__ Wqb,
            bf16_t* __restrict__ MT) {
  __shared__ bf16_t lds[65536];
  const int bid = blockIdx.x;          // 256 blocks
  const int mb = bid & 3, nb = (bid >> 2) & 3, h = bid >> 4;
  f32x4 acc[8][4] = {};
  mm256_core(Wkb + ((size_t)h * 1024 + mb * 256) * 1024,
             Wqb + ((size_t)h * 1024 + nb * 256) * 1024, lds, acc);
  epi256_bf16(acc, lds,
              MT + ((size_t)h * 1024 + mb * 256) * 1024 + nb * 256, 1024);
}

// ---------------------------------------------------------------------------
// t_gemm: T[bh][i][d'] = sum_d x[b][i][d] MT[h][d'][d]
// ---------------------------------------------------------------------------
__global__ __launch_bounds__(512)
void t_gemm(const bf16_t* __restrict__ xb, const bf16_t* __restrict__ MT,
            bf16_t* __restrict__ T) {
  __shared__ bf16_t lds[65536];
  const int bid = blockIdx.x;                      // 1024 blocks
  const int lid = (bid & 7) * 128 + (bid >> 3);    // XCD swizzle
  const int mb = lid & 15, nb = (lid >> 4) & 3, h = lid >> 6;
  f32x4 acc[8][4] = {};
  mm256_core(xb + (size_t)mb * 256 * 1024,
             MT + ((size_t)h * 1024 + nb * 256) * 1024, lds, acc);
  const int b = mb >> 2;
  const int bh = b * 16 + h;
  epi256_bf16(acc, lds,
              T + (size_t)bh * 1024 * 1024 + (size_t)((mb & 3) * 256) * 1024 +
                  nb * 256, 1024);
}

// ---------------------------------------------------------------------------
// s_gemm256: S = (T.x^T + u_i + v_j) * SCALE, lower-triangle 256^2 tiles,
// all 64 bh (640 blocks); bf16 out.
// ---------------------------------------------------------------------------
__global__ __launch_bounds__(512)
void s_gemm256(const bf16_t* __restrict__ T, const bf16_t* __restrict__ xb,
               const float* __restrict__ u, const float* __restrict__ v,
               bf16_t* __restrict__ Sg) {
  __shared__ bf16_t lds[65536];
  const int bid = blockIdx.x;                 // 0..639
  const int lid = (bid & 7) * 80 + (bid >> 3);
  const int idx = lid % 10;
  const int bh = lid / 10;
  const int bb = bh >> 4;
  int qt = 0;
  while ((qt + 1) * (qt + 2) / 2 <= idx) ++qt;
  const int kt = idx - qt * (qt + 1) / 2;

  f32x4 acc[8][4] = {};
  mm256_core(T + (size_t)bh * 1024 * 1024 + (size_t)qt * 256 * 1024,
             xb + (size_t)bb * 1024 * 1024 + (size_t)kt * 256 * 1024, lds, acc);

  const int t = threadIdx.x;
  const int w = t >> 6, l = t & 63, l15 = l & 15, lg = l >> 4;
  const int wm = w >> 2, wn = w & 3;
  const float SCALE = 0.045084220027780106f;   // log2(e)/sqrt(1024)
  bf16_t* So = Sg + (((size_t)bh * 10 + idx) << 16);

  const float* ubh = u + (size_t)bh * 1024 + qt * 256;
  const float* vbh = v + (size_t)bh * 1024 + kt * 256;
  float vv[4];
  #pragma unroll
  for (int ni = 0; ni < 4; ++ni) vv[ni] = vbh[wn * 64 + ni * 16 + l15];

  #pragma unroll
  for (int mi = 0; mi < 8; ++mi)
    #pragma unroll
    for (int r = 0; r < 4; ++r) {
      int rl = wm * 128 + mi * 16 + lg * 4 + r;
      float uu = ubh[rl];
      #pragma unroll
      for (int ni = 0; ni < 4; ++ni) {
        int cl = wn * 64 + ni * 16 + l15;
        float z = (acc[mi][ni][r] + uu + vv[ni]) * SCALE;
        if (kt * 256 + cl > qt * 256 + rl) z = -1e30f;
        acc[mi][ni][r] = z;
      }
    }

  epi256_bf16(acc, lds, So, 256);
}

// ---------------------------------------------------------------------------
// softmax + P.V (bf16 S)
// ---------------------------------------------------------------------------
__global__ __launch_bounds__(256)
void softmax_pv(const bf16_t* __restrict__ Sg, const bf16_t* __restrict__ Vt,
                bf16_t* __restrict__ sa) {
  const int qt = blockIdx.x;   // 0..15
  const int bh = blockIdx.y;   // 0..63
  const int t = threadIdx.x;
  const int w = t >> 6, l = t & 63, l15 = l & 15, lg = l >> 4;
  const int b = bh >> 4, h = bh & 15;

  const int qrow = qt * 64 + w * 16 + l15;
  const int qt8 = qt >> 2;
  const bf16_t* Sbh = Sg + (((size_t)bh * 10) << 16);
  const bf16_t* Vh = Vt + (size_t)bh * DH_ * N_;

  f32x4 accO[4] = {};
  float m = -1e30f, lsum = 0.f;

  for (int j = 0; j <= qt; ++j) {
    const int jb = j * 64;
    const int tid = qt8 * (qt8 + 1) / 2 + (j >> 2);
    const bf16_t* Srow = Sbh + ((size_t)tid << 16) +
                         (size_t)(qrow & 255) * 256 + (jb & 255);

    bf16x8 h0 = *(const bf16x8*)(Srow + lg * 8);
    bf16x8 h1 = *(const bf16x8*)(Srow + 32 + lg * 8);
    float z[16];
    #pragma unroll
    for (int i = 0; i < 8; ++i) z[i] = (float)h0[i];
    #pragma unroll
    for (int i = 0; i < 8; ++i) z[8 + i] = (float)h1[i];

    float zm = z[0];
    #pragma unroll
    for (int i = 1; i < 16; ++i) zm = fmaxf(zm, z[i]);
    zm = fmaxf(zm, __shfl_xor(zm, 16));
    zm = fmaxf(zm, __shfl_xor(zm, 32));

    float mnew = fmaxf(m, zm);
    float scl = exp2f(m - mnew);
    m = mnew;

    float p[16];
    #pragma unroll
    for (int i = 0; i < 16; ++i) p[i] = exp2f(z[i] - mnew);

    float rs = 0.f;
    #pragma unroll
    for (int i = 0; i < 16; ++i) rs += p[i];
    rs += __shfl_xor(rs, 16);
    rs += __shfl_xor(rs, 32);
    lsum = lsum * scl + rs;

    float sclO[4];
    #pragma unroll
    for (int r = 0; r < 4; ++r) sclO[r] = __shfl(scl, lg * 4 + r);
    #pragma unroll
    for (int db = 0; db < 4; ++db)
      #pragma unroll
      for (int r = 0; r < 4; ++r) accO[db][r] *= sclO[r];

    bf16x8 pa0 = {(bf16_t)p[0], (bf16_t)p[1], (bf16_t)p[2], (bf16_t)p[3],
                  (bf16_t)p[4], (bf16_t)p[5], (bf16_t)p[6], (bf16_t)p[7]};
    bf16x8 pa1 = {(bf16_t)p[8], (bf16_t)p[9], (bf16_t)p[10], (bf16_t)p[11],
                  (bf16_t)p[12], (bf16_t)p[13], (bf16_t)p[14], (bf16_t)p[15]};

    #pragma unroll
    for (int db = 0; db < 4; ++db) {
      const bf16_t* vp = Vh + (size_t)(db * 16 + l15) * N_ + jb;
      bf16x8 vb0 = *(const bf16x8*)(vp + lg * 8);
      bf16x8 vb1 = *(const bf16x8*)(vp + 32 + lg * 8);
      accO[db] = __builtin_amdgcn_mfma_f32_16x16x32_bf16(pa0, vb0, accO[db], 0, 0, 0);
      accO[db] = __builtin_amdgcn_mfma_f32_16x16x32_bf16(pa1, vb1, accO[db], 0, 0, 0);
    }
  }

  float lO[4];
  #pragma unroll
  for (int r = 0; r < 4; ++r) lO[r] = __shfl(lsum, lg * 4 + r);

  #pragma unroll
  for (int db = 0; db < 4; ++db)
    #pragma unroll
    for (int r = 0; r < 4; ++r) {
      int row = qt * 64 + w * 16 + lg * 4 + r;
      int col = h * DH_ + db * 16 + l15;
      sa[((size_t)b * N_ + row) * D_ + col] = (bf16_t)(accO[db][r] / lO[r]);
    }
}

// ---------------------------------------------------------------------------
// out_gemm (m97 128^2 structure, fp32 out)
// ---------------------------------------------------------------------------
__global__ __launch_bounds__(256)
void out_gemm(const bf16_t* __restrict__ A, const bf16_t* __restrict__ Bt,
              const float* __restrict__ bp, float* __restrict__ out) {
  const int mb = blockIdx.x, nb = blockIdx.y;
  const int t = threadIdx.x;
  const int w = t >> 6, l = t & 63, l15 = l & 15, lg = l >> 4;
  const int wr = (w >> 1) * 64, wc = (w & 1) * 64;

  __shared__ bf16_t As[128 * 64];
  __shared__ bf16_t Bs[128 * 64];

  const int srow = w * 32 + (l >> 3);
  const int scol = (l & 7) * 8;
  const bf16_t* ag = A + (size_t)(mb * 128 + srow) * D_ + scol;
  const bf16_t* bg = Bt + (size_t)(nb * 128 + srow) * D_ + scol;
  char* asl = (char*)As + w * 4096;
  char* bsl = (char*)Bs + w * 4096;

  f32x4 acc[4][4] = {};

  for (int kb = 0; kb < 16; ++kb) {
    __syncthreads();
    #pragma unroll
    for (int i = 0; i < 4; ++i) {
      gload_lds16(ag + (size_t)i * 8 * D_ + kb * 64, asl + i * 1024);
      gload_lds16(bg + (size_t)i * 8 * D_ + kb * 64, bsl + i * 1024);
    }
    __syncthreads();
    #pragma unroll
    for (int ks = 0; ks < 2; ++ks) {
      bf16x8 a[4], b[4];
      #pragma unroll
      for (int mi = 0; mi < 4; ++mi)
        a[mi] = *(const bf16x8*)((const char*)As + (wr + mi * 16 + l15) * 128 + ks * 64 + lg * 16);
      #pragma unroll
      for (int ni = 0; ni < 4; ++ni)
        b[ni] = *(const bf16x8*)((const char*)Bs + (wc + ni * 16 + l15) * 128 + ks * 64 + lg * 16);
      #pragma unroll
      for (int mi = 0; mi < 4; ++mi)
        #pragma unroll
        for (int ni = 0; ni < 4; ++ni)
          acc[mi][ni] = __builtin_amdgcn_mfma_f32_16x16x32_bf16(a[mi], b[ni], acc[mi][ni], 0, 0, 0);
    }
  }

  #pragma unroll
  for (int ni = 0; ni < 4; ++ni) {
    int e = nb * 128 + wc + ni * 16 + l15;
    float bias = bp[e];
    #pragma unroll
    for (int mi = 0; mi < 4; ++mi)
      #pragma unroll
      for (int r = 0; r < 4; ++r) {
        int grow = mb * 128 + wr + mi * 16 + lg * 4 + r;
        out[(size_t)grow * D_ + e] = acc[mi][ni][r] + bias;
      }
  }
}

// ---------------------------------------------------------------------------
extern "C" void kernel_launch(void* const* d_in, const int* in_sizes, int n_in,
                              void* d_out, int out_size, void* d_ws, size_t ws_size,
                              hipStream_t stream) {
  const float* x    = (const float*)d_in[0];
  const float* Wkqv = (const float*)d_in[1];
  const float* bkqv = (const float*)d_in[2];
  const float* Wp   = (const float*)d_in[3];
  const float* bp   = (const float*)d_in[4];
  float* out = (float*)d_out;
  char* ws = (char*)d_ws;

  const size_t MB = 1 << 20;
  bf16_t* xb   = (bf16_t*)(ws);              //   8 MiB
  bf16_t* sa   = (bf16_t*)(ws + 8 * MB);     //   8 MiB
  bf16_t* Wpt  = (bf16_t*)(ws + 16 * MB);    //   2 MiB
  bf16_t* Vt   = (bf16_t*)(ws + 18 * MB);    //   8 MiB
  bf16_t* Wvt  = (bf16_t*)(ws + 26 * MB);    //   2 MiB
  bf16_t* MT   = (bf16_t*)(ws + 28 * MB);    //  32 MiB
  bf16_t* T    = (bf16_t*)(ws + 60 * MB);    // 128 MiB
  bf16_t* Wqb  = (bf16_t*)(ws + 188 * MB);   //  32 MiB (dead after m_gemm)
  bf16_t* Wkb  = (bf16_t*)(ws + 220 * MB);   //  32 MiB (dead after m_gemm)
  bf16_t* Sg   = (bf16_t*)(ws + 188 * MB);   //  80 MiB (reuses Wqb/Wkb)
  float*  u    = (float*) (ws + 268 * MB);               // 256 KiB
  float*  v    = (float*) (ws + 268 * MB + 256 * 1024);  // 256 KiB
  float*  wqbk = (float*) (ws + 268 * MB + 512 * 1024);  // 64 KiB
  float*  wkbq = (float*) (ws + 268 * MB + 576 * 1024);  // 64 KiB
  float*  bqk  = (float*) (ws + 268 * MB + 640 * 1024);  // 64 B
  // top < 269 MiB < proven-safe 285,212,672 B

  hipLaunchKernelGGL(prep_all, dim3(4112), dim3(256), 0, stream,
                     x, Wp, Wkqv, bkqv, xb, Wpt, Wvt, bqk,
                     Wqb, Wkb, wqbk, wkbq);
  hipLaunchKernelGGL(uv_v, dim3(1536), dim3(256), 0, stream,
                     x, bqk, wqbk, wkbq, u, v, xb, Wvt, bkqv, Vt);
  hipLaunchKernelGGL(m_gemm, dim3(256), dim3(512), 0, stream, Wkb, Wqb, MT);
  hipLaunchKernelGGL(t_gemm, dim3(1024), dim3(512), 0, stream, xb, MT, T);
  hipLaunchKernelGGL(s_gemm256, dim3(640), dim3(512), 0, stream,
                     T, xb, u, v, Sg);
  hipLaunchKernelGGL(softmax_pv, dim3(16, 64), dim3(256), 0, stream,
                     Sg, Vt, sa);
  hipLaunchKernelGGL(out_gemm, dim3(32, 8), dim3(256), 0, stream,
                     sa, Wpt, bp, out);
}